// Round 1
// baseline (1230.308 us; speedup 1.0000x reference)
//
#include <hip/hip_runtime.h>
#include <hip/hip_bf16.h>

// MultiScaleAttention on MI355X (gfx950).
// cvt(x)->bf16; QKV GEMM (bf16 MFMA, fp32 acc, XOR-swizzled LDS);
// MFMA windowed attention; proj GEMM -> fp32 out. Unchunked (ws ~660MB ok).
// R1: XCD-aware block swizzle (A-panel L2 locality across the 18 N-blocks/row)
//     + swapped-operand epilogue (lane owns 4 consecutive C cols -> 8B/16B
//     packed stores, 16 stores/thread instead of 64 scattered ushort stores).

typedef __bf16 bf16x8 __attribute__((ext_vector_type(8)));
typedef float f32x4 __attribute__((ext_vector_type(4)));
typedef unsigned short u16x8 __attribute__((ext_vector_type(8)));

#define GLOBAL_AS __attribute__((address_space(1)))
#define LDS_AS __attribute__((address_space(3)))

__device__ __forceinline__ unsigned short f2bf(float f) {
    unsigned u = __builtin_bit_cast(unsigned, f);
    u += 0x7FFFu + ((u >> 16) & 1u);           // round-to-nearest-even
    return (unsigned short)(u >> 16);
}
__device__ __forceinline__ float bf2f(unsigned short h) {
    return __builtin_bit_cast(float, (unsigned)h << 16);
}

__device__ __forceinline__ void load16_to_lds(const void* g, void* l) {
    __builtin_amdgcn_global_load_lds((const GLOBAL_AS unsigned int*)g,
                                     (LDS_AS unsigned int*)l, 16, 0, 0);
}

// ---------------- elementwise fp32 -> bf16 ----------------
__global__ void cvt_f32_bf16(const float* __restrict__ in,
                             unsigned short* __restrict__ out, long n4) {
    long i = (long)blockIdx.x * blockDim.x + threadIdx.x;
    if (i >= n4) return;
    float4 f = ((const float4*)in)[i];
    uint2 u;
    u.x = (unsigned)f2bf(f.x) | ((unsigned)f2bf(f.y) << 16);
    u.y = (unsigned)f2bf(f.z) | ((unsigned)f2bf(f.w) << 16);
    ((uint2*)out)[i] = u;
}

// ---------------- W[K][N] fp32 -> Wt[N][K] bf16 ----------------
__global__ void transpose_cvt(const float* __restrict__ W,
                              unsigned short* __restrict__ Wt, int K, int N) {
    __shared__ float tile[32][33];
    int bx = blockIdx.x * 32;                  // N offset
    int by = blockIdx.y * 32;                  // K offset
    int tx = threadIdx.x & 31, ty = threadIdx.x >> 5;   // ty 0..7
    #pragma unroll
    for (int i = 0; i < 32; i += 8)
        tile[ty + i][tx] = W[(size_t)(by + ty + i) * N + bx + tx];
    __syncthreads();
    #pragma unroll
    for (int i = 0; i < 32; i += 8)
        Wt[(size_t)(bx + ty + i) * K + by + tx] = f2bf(tile[tx][ty + i]);
}

// ---------------- bf16 GEMM: C[M,N] = A[M,K] @ Bt[N,K]^T + bias ----------------
// 128x128 tile, BK=64, 256 threads = 4 waves (2x2 of 64x64), mfma 16x16x32.
// LDS XOR swizzle: physical 16B chunk p of row r holds logical chunk p^(r&7).
// Staging permutes the GLOBAL source chunk per lane (global_load_lds dest is
// fixed at base+lane*16); fragment reads XOR the column. Kills the 16-way
// bank conflict of the 128B-row-stride layout (r2: SQ_LDS_BANK_CONFLICT 1.3e8).
// Block index is XCD-swizzled (bijective, nwg % 8 == 0 guaranteed by launcher)
// so each XCD's private L2 sees a contiguous M-chunk -> A panels fetched ~once.
// MFMA operands are SWAPPED vs the A/B naming: acc[i][j] = mfma(bg[j], af[i])
// puts row = wm+i*16+(lane&15) (constant per lane) and col = wn+j*16+quad*4+r
// (4 consecutive cols in the 4 acc regs) -> packed 8B/16B stores.
template <bool OUT_BF16>
__global__ __launch_bounds__(256)
void gemm_bt(const unsigned short* __restrict__ A,
             const unsigned short* __restrict__ Bt,
             const float* __restrict__ bias,
             void* __restrict__ Cv, int M, int N, int K) {
    __shared__ alignas(16) unsigned short lsA[128 * 64];
    __shared__ alignas(16) unsigned short lsB[128 * 64];

    const int tid  = threadIdx.x;
    const int lane = tid & 63;
    const int wave = tid >> 6;
    const int wm = (wave >> 1) * 64;
    const int wn = (wave & 1) * 64;

    // XCD-aware bijective swizzle: hw-consecutive blocks round-robin XCDs;
    // remap so XCD x gets logical tiles [x*cpx, (x+1)*cpx) (contiguous M rows).
    const int nwg = (int)(gridDim.x * gridDim.y);
    const int hid = (int)(blockIdx.y * gridDim.x + blockIdx.x);
    int lid = hid;
    if ((nwg & 7) == 0) {
        const int cpx = nwg >> 3;
        lid = (hid & 7) * cpx + (hid >> 3);
    }
    const int tileX = lid % (int)gridDim.x;
    const int tileY = lid / (int)gridDim.x;
    const long bm = (long)tileY * 128;
    const long bn = (long)tileX * 128;

    const int arow  = tid >> 3;                               // 0..31, +32 per it
    const int acolb = (((tid & 7) ^ ((tid >> 3) & 7)) * 16);  // swizzled byte col
    const char* gA = (const char*)A + ((bm + arow) * (long)K) * 2 + acolb;
    const char* gB = (const char*)Bt + ((bn + arow) * (long)K) * 2 + acolb;
    const long rowStep = (long)K * 2 * 32;     // 32 rows ahead per 'it' (row&7 invariant)
    const int ldsWaveBase = wave * 512;        // ushort units

    f32x4 acc[4][4] = {};

    for (int kt = 0; kt < K; kt += 64) {
        #pragma unroll
        for (int it = 0; it < 4; ++it) {
            load16_to_lds(gA + it * rowStep, &lsA[it * 2048 + ldsWaveBase]);
            load16_to_lds(gB + it * rowStep, &lsB[it * 2048 + ldsWaveBase]);
        }
        gA += 128; gB += 128;                  // advance 64 bf16 in K
        __syncthreads();
        #pragma unroll
        for (int ks = 0; ks < 64; ks += 32) {
            bf16x8 af[4], bg[4];
            // rowA&7 == lane&7 for all i (wm, i*16 are multiples of 8)
            const int colSwz = (ks + ((lane >> 4) & 3) * 8) ^ ((lane & 7) * 8);
            #pragma unroll
            for (int i = 0; i < 4; ++i) {
                const int rowA = wm + i * 16 + (lane & 15);
                af[i] = *(const bf16x8*)&lsA[rowA * 64 + colSwz];
                const int rowB = wn + i * 16 + (lane & 15);
                bg[i] = *(const bf16x8*)&lsB[rowB * 64 + colSwz];
            }
            #pragma unroll
            for (int i = 0; i < 4; ++i)
                #pragma unroll
                for (int j = 0; j < 4; ++j)
                    acc[i][j] = __builtin_amdgcn_mfma_f32_16x16x32_bf16(
                        bg[j], af[i], acc[i][j], 0, 0, 0);
        }
        __syncthreads();
    }

    // Epilogue: lane owns row = bm+wm+i*16+(lane&15), cols col0+r (r=0..3).
    const int lane15 = lane & 15;
    const int quad   = lane >> 4;
    const long rbase = bm + wm + lane15;
    const int  cbase = (int)bn + wn + quad * 4;
    #pragma unroll
    for (int j = 0; j < 4; ++j) {
        const int col = cbase + j * 16;
        const float4 bv = *(const float4*)&bias[col];
        #pragma unroll
        for (int i = 0; i < 4; ++i) {
            const long row = rbase + i * 16;
            const size_t idx = (size_t)row * N + col;
            const float v0 = acc[i][j][0] + bv.x;
            const float v1 = acc[i][j][1] + bv.y;
            const float v2 = acc[i][j][2] + bv.z;
            const float v3 = acc[i][j][3] + bv.w;
            if constexpr (OUT_BF16) {
                ushort4 s;
                s.x = f2bf(v0); s.y = f2bf(v1); s.z = f2bf(v2); s.w = f2bf(v3);
                *(ushort4*)((unsigned short*)Cv + idx) = s;
            } else {
                float4 s;
                s.x = v0; s.y = v1; s.z = v2; s.w = v3;
                *(float4*)((float*)Cv + idx) = s;
            }
        }
    }
}

// ---------------- MFMA windowed attention ----------------
// One wave = one (b, w, head). 4 waves/block -> 4 heads (hg*4 + wave).
// qkv rows: token n = t*49 + w (t in [0,64)), cols sec*768 + h*64 + d.
// Pool q over token groups {j, j+16, j+32, j+48} -> qp[16][64] (in regs,
// pre-scaled by 0.125). S = qp @ k^T via 8 mfma (k frags from global).
// Softmax across 16 lanes + 4 n-tiles. P -> LDS -> A-frags. v staged
// transposed in LDS -> B-frags. O = P@v via 8 mfma. No __syncthreads.
__global__ __launch_bounds__(256)
void attn_win_mfma(const unsigned short* __restrict__ qkv,
                   unsigned short* __restrict__ o) {
    const int hg = blockIdx.x;       // 0..2
    const int w  = blockIdx.y;       // 0..48
    const int b  = blockIdx.z;       // batch within chunk
    const int wave = threadIdx.x >> 6;
    const int lane = threadIdx.x & 63;
    const int h = hg * 4 + wave;
    const int l = lane & 15;
    const int quad = lane >> 4;

    __shared__ alignas(16) unsigned short vT[4][64 * 72];  // [d][t], stride 72
    __shared__ alignas(16) unsigned short ps[4][16 * 72];  // P[q][key], stride 72

    const long tokStride = 49L * 2304;
    const long base = ((long)b * 3136 + w) * 2304 + h * 64;

    // ---- q load + max-pool + 0.125 scale (exact in bf16) -> A-frags ----
    bf16x8 af[2];
    {
        const unsigned short* qr = qkv + base + (long)l * tokStride + quad * 8;
        float m0[8], m1[8];
        #pragma unroll
        for (int sg = 0; sg < 4; ++sg) {
            uint4 u0 = *(const uint4*)(qr + (long)sg * 16 * tokStride);
            uint4 u1 = *(const uint4*)(qr + (long)sg * 16 * tokStride + 32);
            const unsigned short* p0 = (const unsigned short*)&u0;
            const unsigned short* p1 = (const unsigned short*)&u1;
            #pragma unroll
            for (int e = 0; e < 8; ++e) {
                float f0 = bf2f(p0[e]), f1 = bf2f(p1[e]);
                if (sg == 0) { m0[e] = f0; m1[e] = f1; }
                else { m0[e] = fmaxf(m0[e], f0); m1[e] = fmaxf(m1[e], f1); }
            }
        }
        u16x8 a0, a1;
        #pragma unroll
        for (int e = 0; e < 8; ++e) {
            a0[e] = f2bf(m0[e] * 0.125f);
            a1[e] = f2bf(m1[e] * 0.125f);
        }
        af[0] = __builtin_bit_cast(bf16x8, a0);
        af[1] = __builtin_bit_cast(bf16x8, a1);
    }

    // ---- v: stage transposed into LDS ----
    {
        const unsigned short* vr = qkv + base + (long)lane * tokStride + 1536;
        unsigned short* vw = &vT[wave][0];
        #pragma unroll
        for (int i = 0; i < 8; ++i) {
            uint4 u = *(const uint4*)(vr + i * 8);
            const unsigned short* pe = (const unsigned short*)&u;
            #pragma unroll
            for (int e = 0; e < 8; ++e)
                vw[(i * 8 + e) * 72 + lane] = pe[e];
        }
    }

    // ---- k B-frags from global; S = qp @ k^T ----
    f32x4 Sc[4] = {};
    {
        bf16x8 bk0, bk1;
        #pragma unroll
        for (int tt = 0; tt < 4; ++tt) {
            const unsigned short* kr =
                qkv + base + (long)(tt * 16 + l) * tokStride + 768 + quad * 8;
            bk0 = __builtin_bit_cast(bf16x8, *(const uint4*)kr);
            bk1 = __builtin_bit_cast(bf16x8, *(const uint4*)(kr + 32));
            Sc[tt] = __builtin_amdgcn_mfma_f32_16x16x32_bf16(af[0], bk0, Sc[tt], 0, 0, 0);
            Sc[tt] = __builtin_amdgcn_mfma_f32_16x16x32_bf16(af[1], bk1, Sc[tt], 0, 0, 0);
        }
    }

    // ---- softmax: row q = quad*4+r, keys spread over 4 tt x 16 lanes ----
    float pr[4][4];
    {
        #pragma unroll
        for (int r = 0; r < 4; ++r) {
            float mx = fmaxf(fmaxf(Sc[0][r], Sc[1][r]), fmaxf(Sc[2][r], Sc[3][r]));
            #pragma unroll
            for (int off = 1; off < 16; off <<= 1)
                mx = fmaxf(mx, __shfl_xor(mx, off));
            float sum = 0.f;
            #pragma unroll
            for (int tt = 0; tt < 4; ++tt) {
                pr[tt][r] = __expf(Sc[tt][r] - mx);
                sum += pr[tt][r];
            }
            #pragma unroll
            for (int off = 1; off < 16; off <<= 1)
                sum += __shfl_xor(sum, off);
            const float inv = 1.0f / sum;
            #pragma unroll
            for (int tt = 0; tt < 4; ++tt) pr[tt][r] *= inv;
        }
    }

    // ---- P -> LDS (bf16) ----
    {
        unsigned short* pw = &ps[wave][0];
        #pragma unroll
        for (int r = 0; r < 4; ++r)
            #pragma unroll
            for (int tt = 0; tt < 4; ++tt)
                pw[(quad * 4 + r) * 72 + tt * 16 + l] = f2bf(pr[tt][r]);
    }

    // ---- O = P @ v ----
    f32x4 Oc[4] = {};
    {
        #pragma unroll
        for (int s = 0; s < 2; ++s) {
            bf16x8 ap = *(const bf16x8*)&ps[wave][l * 72 + s * 32 + quad * 8];
            #pragma unroll
            for (int tt = 0; tt < 4; ++tt) {
                bf16x8 bv = *(const bf16x8*)&vT[wave][(tt * 16 + l) * 72 + s * 32 + quad * 8];
                Oc[tt] = __builtin_amdgcn_mfma_f32_16x16x32_bf16(ap, bv, Oc[tt], 0, 0, 0);
            }
        }
    }

    // ---- store: o row = b*784 + q*49 + w, col = h*64 + tt*16 + l ----
    {
        const long obase = ((long)b * 784 + (long)(quad * 4) * 49 + w) * 768 + h * 64 + l;
        #pragma unroll
        for (int tt = 0; tt < 4; ++tt)
            #pragma unroll
            for (int r = 0; r < 4; ++r)
                o[obase + (long)r * 49 * 768 + tt * 16] = f2bf(Oc[tt][r]);
    }
}

// ---------------- launcher ----------------
extern "C" void kernel_launch(void* const* d_in, const int* in_sizes, int n_in,
                              void* d_out, int out_size, void* d_ws, size_t ws_size,
                              hipStream_t stream) {
    const float* x     = (const float*)d_in[0];  // [32,3136,768]
    const float* Wqkv  = (const float*)d_in[1];  // [768,2304]
    const float* bqkv  = (const float*)d_in[2];  // [2304]
    const float* Wproj = (const float*)d_in[3];  // [768,768]
    const float* bproj = (const float*)d_in[4];  // [768]
    float* out = (float*)d_out;                  // [32,784,768] fp32

    const long needed1 = (32L * 3136 * 768 + 32L * 3136 * 2304 +
                          25088L * 768 + 2304L * 768 + 768L * 768) * 2;
    const int C  = (ws_size >= (size_t)needed1) ? 1 : 4;   // unchunked if ws allows
    const int CB = 32 / C;
    const long XC = (long)CB * 3136 * 768;
    const long QC = (long)CB * 3136 * 2304;

    char* p = (char*)d_ws;
    unsigned short* xb    = (unsigned short*)p; p += XC * 2;
    unsigned short* qkvb  = (unsigned short*)p; p += QC * 2;
    unsigned short* ob    = (unsigned short*)p; p += 25088L * 768 * 2;
    unsigned short* WqkvT = (unsigned short*)p; p += 2304L * 768 * 2;
    unsigned short* WprojT= (unsigned short*)p; p += 768L * 768 * 2;

    transpose_cvt<<<dim3(72, 24), 256, 0, stream>>>(Wqkv, WqkvT, 768, 2304);
    transpose_cvt<<<dim3(24, 24), 256, 0, stream>>>(Wproj, WprojT, 768, 768);

    const int M = CB * 3136;
    for (int c = 0; c < C; ++c) {
        cvt_f32_bf16<<<(int)(XC / 4 / 256), 256, 0, stream>>>(x + (size_t)c * XC, xb, XC / 4);
        gemm_bt<true><<<dim3(18, M / 128), 256, 0, stream>>>(
            xb, WqkvT, bqkv, qkvb, M, 2304, 768);
        attn_win_mfma<<<dim3(3, 49, CB), 256, 0, stream>>>(
            qkvb, ob + (size_t)c * CB * 784 * 768);
    }
    gemm_bt<false><<<dim3(6, 196), 256, 0, stream>>>(
        ob, WprojT, bproj, out, 25088, 768, 768);
}

// Round 2
// 1177.922 us; speedup vs baseline: 1.0445x; 1.0445x over previous
//
#include <hip/hip_runtime.h>
#include <hip/hip_bf16.h>

// MultiScaleAttention on MI355X (gfx950).
// cvt(x)->bf16; QKV GEMM (bf16 MFMA, fp32 acc, XOR-swizzled LDS);
// MFMA windowed attention; proj GEMM -> fp32 out. Unchunked (ws ~660MB ok).
// R2: GEMM rewritten as 256x256 tile, 8 waves (2Mx4N), BK=64, double-buffered
//     LDS (128 KiB) with stage-ahead + single barrier per K-tile (T3-minimum).
//     Fixes the two structural limits of the 128^2 2-barrier loop measured in
//     R0/R1 (MfmaUtil 24%, all pipes ~30%): per-K-tile exposed load latency
//     (stage was drained by the barrier immediately after issue) and LDS-read
//     amplification (2x2 wave grid re-reads each fragment; 2x4 grid at 256^2
//     gives MFMA cyc > LDS cyc). XOR swizzle + packed epilogue kept from R1.

typedef __bf16 bf16x8 __attribute__((ext_vector_type(8)));
typedef float f32x4 __attribute__((ext_vector_type(4)));
typedef unsigned short u16x8 __attribute__((ext_vector_type(8)));

#define GLOBAL_AS __attribute__((address_space(1)))
#define LDS_AS __attribute__((address_space(3)))

__device__ __forceinline__ unsigned short f2bf(float f) {
    unsigned u = __builtin_bit_cast(unsigned, f);
    u += 0x7FFFu + ((u >> 16) & 1u);           // round-to-nearest-even
    return (unsigned short)(u >> 16);
}
__device__ __forceinline__ float bf2f(unsigned short h) {
    return __builtin_bit_cast(float, (unsigned)h << 16);
}

__device__ __forceinline__ void load16_to_lds(const void* g, void* l) {
    __builtin_amdgcn_global_load_lds((const GLOBAL_AS unsigned int*)g,
                                     (LDS_AS unsigned int*)l, 16, 0, 0);
}

// ---------------- elementwise fp32 -> bf16 ----------------
__global__ void cvt_f32_bf16(const float* __restrict__ in,
                             unsigned short* __restrict__ out, long n4) {
    long i = (long)blockIdx.x * blockDim.x + threadIdx.x;
    if (i >= n4) return;
    float4 f = ((const float4*)in)[i];
    uint2 u;
    u.x = (unsigned)f2bf(f.x) | ((unsigned)f2bf(f.y) << 16);
    u.y = (unsigned)f2bf(f.z) | ((unsigned)f2bf(f.w) << 16);
    ((uint2*)out)[i] = u;
}

// ---------------- W[K][N] fp32 -> Wt[N][K] bf16 ----------------
__global__ void transpose_cvt(const float* __restrict__ W,
                              unsigned short* __restrict__ Wt, int K, int N) {
    __shared__ float tile[32][33];
    int bx = blockIdx.x * 32;                  // N offset
    int by = blockIdx.y * 32;                  // K offset
    int tx = threadIdx.x & 31, ty = threadIdx.x >> 5;   // ty 0..7
    #pragma unroll
    for (int i = 0; i < 32; i += 8)
        tile[ty + i][tx] = W[(size_t)(by + ty + i) * N + bx + tx];
    __syncthreads();
    #pragma unroll
    for (int i = 0; i < 32; i += 8)
        Wt[(size_t)(bx + ty + i) * K + by + tx] = f2bf(tile[tx][ty + i]);
}

// ---------------- bf16 GEMM: C[M,N] = A[M,K] @ Bt[N,K]^T + bias ----------------
// 256x256 tile, BK=64, 512 threads = 8 waves (2M x 4N, per-wave 128x64 out),
// mfma 16x16x32, fp32 acc. Double-buffered LDS (2 x 64 KiB): STAGE(t+1) is
// issued BEFORE compute(t); the single __syncthreads() per K-tile drains
// vmcnt after the full MFMA phase has covered the load latency.
// LDS XOR swizzle: physical 16B chunk p of row r holds logical chunk p^(r&7);
// staging permutes the GLOBAL source chunk per lane (global_load_lds dest is
// fixed at base+lane*16); fragment reads XOR the column -> 0 bank conflicts.
// Block index: bijective XCD swizzle (m204 general form, any nwg) so each
// XCD's private L2 sees a contiguous M-chunk -> A panels fetched ~once, B
// panel (<=3.5MB) L2-resident.
// MFMA operands SWAPPED vs A/B naming: acc[i][j] = mfma(bg[j], af[i]) puts
// row = wm+i*16+(lane&15) (per-lane constant) and col = wn+j*16+quad*4+r
// (4 consecutive cols in the 4 acc regs) -> packed 8B/16B stores.
template <bool OUT_BF16>
__global__ __launch_bounds__(512, 2)
void gemm_bt256(const unsigned short* __restrict__ A,
                const unsigned short* __restrict__ Bt,
                const float* __restrict__ bias,
                void* __restrict__ Cv, int M, int N, int K) {
    __shared__ alignas(16) unsigned short lsA[2][256 * 64];   // 64 KiB
    __shared__ alignas(16) unsigned short lsB[2][256 * 64];   // 64 KiB

    const int tid  = threadIdx.x;
    const int lane = tid & 63;
    const int wave = tid >> 6;          // 0..7
    const int wm = (wave >> 2) * 128;   // 0 / 128
    const int wn = (wave & 3) * 64;     // 0 / 64 / 128 / 192

    // bijective XCD swizzle (m204): xcd x gets a contiguous chunk of tiles.
    const int nwg = (int)(gridDim.x * gridDim.y);
    const int hid = (int)(blockIdx.y * gridDim.x + blockIdx.x);
    const int q8  = nwg >> 3, r8 = nwg & 7;
    const int xcd = hid & 7;
    const int lid = (xcd < r8 ? xcd * (q8 + 1) : r8 * (q8 + 1) + (xcd - r8) * q8)
                    + (hid >> 3);
    const int tileX = lid % (int)gridDim.x;
    const int tileY = lid / (int)gridDim.x;
    const long bm = (long)tileY * 256;
    const long bn = (long)tileX * 256;

    // staging addresses: thread covers row = slot*64 + (tid>>3), chunk tid&7
    // (matches global_load_lds dest = wave-uniform base + lane*16).
    const int arow  = tid >> 3;                               // 0..63
    const int acolb = (((tid & 7) ^ (arow & 7)) * 16);        // swizzled byte col
    const char* gA = (const char*)A + ((bm + arow) * (long)K) * 2 + acolb;
    const char* gB = (const char*)Bt + ((bn + arow) * (long)K) * 2 + acolb;
    const long rowStep = (long)K * 2 * 64;     // 64 rows per slot (row&7 invariant)
    const int ldsWaveBase = wave * 512;        // ushort units (8 rows)

    f32x4 acc[8][4] = {};

    const int NT = K >> 6;                     // 12 for K=768

    auto STAGE = [&](int buf, int t) {
        const char* a = gA + (long)t * 128;    // 64 bf16 = 128 B per K-tile
        const char* b = gB + (long)t * 128;
        #pragma unroll
        for (int it = 0; it < 4; ++it) {
            load16_to_lds(a + it * rowStep, &lsA[buf][it * 4096 + ldsWaveBase]);
            load16_to_lds(b + it * rowStep, &lsB[buf][it * 4096 + ldsWaveBase]);
        }
    };

    STAGE(0, 0);
    int cur = 0;
    const int lane15 = lane & 15;
    const int quad   = lane >> 4;

    for (int t = 0; t < NT; ++t) {
        __syncthreads();                       // drain stage of buf[cur] + barrier
        if (t + 1 < NT) STAGE(cur ^ 1, t + 1); // in flight across the whole compute
        #pragma unroll
        for (int ks = 0; ks < 64; ks += 32) {
            bf16x8 af[8], bg[4];
            // row&7 == lane&7 for all frags (wm, wn, i*16 are multiples of 8)
            const int colSwz = (ks + quad * 8) ^ ((lane & 7) * 8);
            #pragma unroll
            for (int i = 0; i < 8; ++i)
                af[i] = *(const bf16x8*)&lsA[cur][(wm + i * 16 + lane15) * 64 + colSwz];
            #pragma unroll
            for (int j = 0; j < 4; ++j)
                bg[j] = *(const bf16x8*)&lsB[cur][(wn + j * 16 + lane15) * 64 + colSwz];
            #pragma unroll
            for (int i = 0; i < 8; ++i)
                #pragma unroll
                for (int j = 0; j < 4; ++j)
                    acc[i][j] = __builtin_amdgcn_mfma_f32_16x16x32_bf16(
                        bg[j], af[i], acc[i][j], 0, 0, 0);
        }
        cur ^= 1;
    }

    // Epilogue: lane owns row = bm+wm+i*16+(lane&15), cols col0..col0+3.
    const long rbase = bm + wm + lane15;
    const int  cbase = (int)bn + wn + quad * 4;
    #pragma unroll
    for (int j = 0; j < 4; ++j) {
        const int col = cbase + j * 16;
        const float4 bv = *(const float4*)&bias[col];
        #pragma unroll
        for (int i = 0; i < 8; ++i) {
            const long row = rbase + i * 16;
            const size_t idx = (size_t)row * N + col;
            const float v0 = acc[i][j][0] + bv.x;
            const float v1 = acc[i][j][1] + bv.y;
            const float v2 = acc[i][j][2] + bv.z;
            const float v3 = acc[i][j][3] + bv.w;
            if constexpr (OUT_BF16) {
                ushort4 s;
                s.x = f2bf(v0); s.y = f2bf(v1); s.z = f2bf(v2); s.w = f2bf(v3);
                *(ushort4*)((unsigned short*)Cv + idx) = s;
            } else {
                float4 s;
                s.x = v0; s.y = v1; s.z = v2; s.w = v3;
                *(float4*)((float*)Cv + idx) = s;
            }
        }
    }
}

// ---------------- MFMA windowed attention ----------------
// One wave = one (b, w, head). 4 waves/block -> 4 heads (hg*4 + wave).
// qkv rows: token n = t*49 + w (t in [0,64)), cols sec*768 + h*64 + d.
// Pool q over token groups {j, j+16, j+32, j+48} -> qp[16][64] (in regs,
// pre-scaled by 0.125). S = qp @ k^T via 8 mfma (k frags from global).
// Softmax across 16 lanes + 4 n-tiles. P -> LDS -> A-frags. v staged
// transposed in LDS -> B-frags. O = P@v via 8 mfma. No __syncthreads.
__global__ __launch_bounds__(256)
void attn_win_mfma(const unsigned short* __restrict__ qkv,
                   unsigned short* __restrict__ o) {
    const int hg = blockIdx.x;       // 0..2
    const int w  = blockIdx.y;       // 0..48
    const int b  = blockIdx.z;       // batch within chunk
    const int wave = threadIdx.x >> 6;
    const int lane = threadIdx.x & 63;
    const int h = hg * 4 + wave;
    const int l = lane & 15;
    const int quad = lane >> 4;

    __shared__ alignas(16) unsigned short vT[4][64 * 72];  // [d][t], stride 72
    __shared__ alignas(16) unsigned short ps[4][16 * 72];  // P[q][key], stride 72

    const long tokStride = 49L * 2304;
    const long base = ((long)b * 3136 + w) * 2304 + h * 64;

    // ---- q load + max-pool + 0.125 scale (exact in bf16) -> A-frags ----
    bf16x8 af[2];
    {
        const unsigned short* qr = qkv + base + (long)l * tokStride + quad * 8;
        float m0[8], m1[8];
        #pragma unroll
        for (int sg = 0; sg < 4; ++sg) {
            uint4 u0 = *(const uint4*)(qr + (long)sg * 16 * tokStride);
            uint4 u1 = *(const uint4*)(qr + (long)sg * 16 * tokStride + 32);
            const unsigned short* p0 = (const unsigned short*)&u0;
            const unsigned short* p1 = (const unsigned short*)&u1;
            #pragma unroll
            for (int e = 0; e < 8; ++e) {
                float f0 = bf2f(p0[e]), f1 = bf2f(p1[e]);
                if (sg == 0) { m0[e] = f0; m1[e] = f1; }
                else { m0[e] = fmaxf(m0[e], f0); m1[e] = fmaxf(m1[e], f1); }
            }
        }
        u16x8 a0, a1;
        #pragma unroll
        for (int e = 0; e < 8; ++e) {
            a0[e] = f2bf(m0[e] * 0.125f);
            a1[e] = f2bf(m1[e] * 0.125f);
        }
        af[0] = __builtin_bit_cast(bf16x8, a0);
        af[1] = __builtin_bit_cast(bf16x8, a1);
    }

    // ---- v: stage transposed into LDS ----
    {
        const unsigned short* vr = qkv + base + (long)lane * tokStride + 1536;
        unsigned short* vw = &vT[wave][0];
        #pragma unroll
        for (int i = 0; i < 8; ++i) {
            uint4 u = *(const uint4*)(vr + i * 8);
            const unsigned short* pe = (const unsigned short*)&u;
            #pragma unroll
            for (int e = 0; e < 8; ++e)
                vw[(i * 8 + e) * 72 + lane] = pe[e];
        }
    }

    // ---- k B-frags from global; S = qp @ k^T ----
    f32x4 Sc[4] = {};
    {
        bf16x8 bk0, bk1;
        #pragma unroll
        for (int tt = 0; tt < 4; ++tt) {
            const unsigned short* kr =
                qkv + base + (long)(tt * 16 + l) * tokStride + 768 + quad * 8;
            bk0 = __builtin_bit_cast(bf16x8, *(const uint4*)kr);
            bk1 = __builtin_bit_cast(bf16x8, *(const uint4*)(kr + 32));
            Sc[tt] = __builtin_amdgcn_mfma_f32_16x16x32_bf16(af[0], bk0, Sc[tt], 0, 0, 0);
            Sc[tt] = __builtin_amdgcn_mfma_f32_16x16x32_bf16(af[1], bk1, Sc[tt], 0, 0, 0);
        }
    }

    // ---- softmax: row q = quad*4+r, keys spread over 4 tt x 16 lanes ----
    float pr[4][4];
    {
        #pragma unroll
        for (int r = 0; r < 4; ++r) {
            float mx = fmaxf(fmaxf(Sc[0][r], Sc[1][r]), fmaxf(Sc[2][r], Sc[3][r]));
            #pragma unroll
            for (int off = 1; off < 16; off <<= 1)
                mx = fmaxf(mx, __shfl_xor(mx, off));
            float sum = 0.f;
            #pragma unroll
            for (int tt = 0; tt < 4; ++tt) {
                pr[tt][r] = __expf(Sc[tt][r] - mx);
                sum += pr[tt][r];
            }
            #pragma unroll
            for (int off = 1; off < 16; off <<= 1)
                sum += __shfl_xor(sum, off);
            const float inv = 1.0f / sum;
            #pragma unroll
            for (int tt = 0; tt < 4; ++tt) pr[tt][r] *= inv;
        }
    }

    // ---- P -> LDS (bf16) ----
    {
        unsigned short* pw = &ps[wave][0];
        #pragma unroll
        for (int r = 0; r < 4; ++r)
            #pragma unroll
            for (int tt = 0; tt < 4; ++tt)
                pw[(quad * 4 + r) * 72 + tt * 16 + l] = f2bf(pr[tt][r]);
    }

    // ---- O = P @ v ----
    f32x4 Oc[4] = {};
    {
        #pragma unroll
        for (int s = 0; s < 2; ++s) {
            bf16x8 ap = *(const bf16x8*)&ps[wave][l * 72 + s * 32 + quad * 8];
            #pragma unroll
            for (int tt = 0; tt < 4; ++tt) {
                bf16x8 bv = *(const bf16x8*)&vT[wave][(tt * 16 + l) * 72 + s * 32 + quad * 8];
                Oc[tt] = __builtin_amdgcn_mfma_f32_16x16x32_bf16(ap, bv, Oc[tt], 0, 0, 0);
            }
        }
    }

    // ---- store: o row = b*784 + q*49 + w, col = h*64 + tt*16 + l ----
    {
        const long obase = ((long)b * 784 + (long)(quad * 4) * 49 + w) * 768 + h * 64 + l;
        #pragma unroll
        for (int tt = 0; tt < 4; ++tt)
            #pragma unroll
            for (int r = 0; r < 4; ++r)
                o[obase + (long)r * 49 * 768 + tt * 16] = f2bf(Oc[tt][r]);
    }
}

// ---------------- launcher ----------------
extern "C" void kernel_launch(void* const* d_in, const int* in_sizes, int n_in,
                              void* d_out, int out_size, void* d_ws, size_t ws_size,
                              hipStream_t stream) {
    const float* x     = (const float*)d_in[0];  // [32,3136,768]
    const float* Wqkv  = (const float*)d_in[1];  // [768,2304]
    const float* bqkv  = (const float*)d_in[2];  // [2304]
    const float* Wproj = (const float*)d_in[3];  // [768,768]
    const float* bproj = (const float*)d_in[4];  // [768]
    float* out = (float*)d_out;                  // [32,784,768] fp32

    const long needed1 = (32L * 3136 * 768 + 32L * 3136 * 2304 +
                          25088L * 768 + 2304L * 768 + 768L * 768) * 2;
    const int C  = (ws_size >= (size_t)needed1) ? 1 : 4;   // unchunked if ws allows
    const int CB = 32 / C;
    const long XC = (long)CB * 3136 * 768;
    const long QC = (long)CB * 3136 * 2304;

    char* p = (char*)d_ws;
    unsigned short* xb    = (unsigned short*)p; p += XC * 2;
    unsigned short* qkvb  = (unsigned short*)p; p += QC * 2;
    unsigned short* ob    = (unsigned short*)p; p += 25088L * 768 * 2;
    unsigned short* WqkvT = (unsigned short*)p; p += 2304L * 768 * 2;
    unsigned short* WprojT= (unsigned short*)p; p += 768L * 768 * 2;

    transpose_cvt<<<dim3(72, 24), 256, 0, stream>>>(Wqkv, WqkvT, 768, 2304);
    transpose_cvt<<<dim3(24, 24), 256, 0, stream>>>(Wproj, WprojT, 768, 768);

    const int M = CB * 3136;
    for (int c = 0; c < C; ++c) {
        cvt_f32_bf16<<<(int)(XC / 4 / 256), 256, 0, stream>>>(x + (size_t)c * XC, xb, XC / 4);
        gemm_bt256<true><<<dim3(9, M / 256), 512, 0, stream>>>(
            xb, WqkvT, bqkv, qkvb, M, 2304, 768);
        attn_win_mfma<<<dim3(3, 49, CB), 256, 0, stream>>>(
            qkvb, ob + (size_t)c * CB * 784 * 768);
    }
    gemm_bt256<false><<<dim3(3, 98), 512, 0, stream>>>(
        ob, WprojT, bproj, out, 25088, 768, 768);
}

// Round 3
// 1103.950 us; speedup vs baseline: 1.1145x; 1.0670x over previous
//
#include <hip/hip_runtime.h>
#include <hip/hip_bf16.h>

// MultiScaleAttention on MI355X (gfx950).
// cvt(x)->bf16; QKV GEMM (bf16 MFMA, 8-phase counted-vmcnt schedule);
// MFMA windowed attention; proj GEMM -> fp32 out. Unchunked (ws ~660MB ok).
// R3: GEMM moved from 2-phase (621 TF measured = documented 2-phase ceiling,
//     m233) to the 8-phase counted-vmcnt schedule (T3+T4+T5) on the same
//     256x256 / 8-wave / BK=64 geometry:
//     - LDS regions are K-halves: [buf][op][ks] = 256 rows x 32 k, 8 x 16 KiB.
//     - per phase: {ds_read frags || stage 1 region} -> [vmcnt(4) @ ph3/ph7]
//       -> raw s_barrier -> lgkmcnt(0)+sched_barrier -> setprio(1) -> 16 MFMA
//       -> setprio(0) -> raw s_barrier. Raw barriers so the compiler cannot
//       insert the vmcnt(0) drain that capped the 2-phase loop.
//     - region re-stage is >=1 phase after its last reader; reader's
//       lgkmcnt(0) + barrier#2 orders read-before-overwrite.
//     - vmcnt accounting (2 loads/region/wave): prologue 6 regions + vmcnt(4);
//       steady waits vmcnt(4) at ph3/ph7; last iter: ph3 wait = vmcnt(0),
//       future stages skipped, ph7 wait skipped. K=768 -> 12 K-tiles, 6 iters.

typedef __bf16 bf16x8 __attribute__((ext_vector_type(8)));
typedef float f32x4 __attribute__((ext_vector_type(4)));
typedef unsigned short u16x8 __attribute__((ext_vector_type(8)));

#define GLOBAL_AS __attribute__((address_space(1)))
#define LDS_AS __attribute__((address_space(3)))

__device__ __forceinline__ unsigned short f2bf(float f) {
    unsigned u = __builtin_bit_cast(unsigned, f);
    u += 0x7FFFu + ((u >> 16) & 1u);           // round-to-nearest-even
    return (unsigned short)(u >> 16);
}
__device__ __forceinline__ float bf2f(unsigned short h) {
    return __builtin_bit_cast(float, (unsigned)h << 16);
}

__device__ __forceinline__ void load16_to_lds(const void* g, void* l) {
    __builtin_amdgcn_global_load_lds((const GLOBAL_AS unsigned int*)g,
                                     (LDS_AS unsigned int*)l, 16, 0, 0);
}

// ---------------- elementwise fp32 -> bf16 ----------------
__global__ void cvt_f32_bf16(const float* __restrict__ in,
                             unsigned short* __restrict__ out, long n4) {
    long i = (long)blockIdx.x * blockDim.x + threadIdx.x;
    if (i >= n4) return;
    float4 f = ((const float4*)in)[i];
    uint2 u;
    u.x = (unsigned)f2bf(f.x) | ((unsigned)f2bf(f.y) << 16);
    u.y = (unsigned)f2bf(f.z) | ((unsigned)f2bf(f.w) << 16);
    ((uint2*)out)[i] = u;
}

// ---------------- W[K][N] fp32 -> Wt[N][K] bf16 ----------------
__global__ void transpose_cvt(const float* __restrict__ W,
                              unsigned short* __restrict__ Wt, int K, int N) {
    __shared__ float tile[32][33];
    int bx = blockIdx.x * 32;                  // N offset
    int by = blockIdx.y * 32;                  // K offset
    int tx = threadIdx.x & 31, ty = threadIdx.x >> 5;   // ty 0..7
    #pragma unroll
    for (int i = 0; i < 32; i += 8)
        tile[ty + i][tx] = W[(size_t)(by + ty + i) * N + bx + tx];
    __syncthreads();
    #pragma unroll
    for (int i = 0; i < 32; i += 8)
        Wt[(size_t)(bx + ty + i) * K + by + tx] = f2bf(tile[tx][ty + i]);
}

// ---------------- bf16 GEMM: C[M,N] = A[M,K] @ Bt[N,K]^T + bias ----------------
// 256x256 tile, BK=64, 512 threads = 8 waves (2M x 4N, per-wave 128x64 out),
// mfma 16x16x32, fp32 acc. 8-phase counted-vmcnt schedule (see header).
// LDS region (16 KiB): 256 rows x 32 k bf16, row = 4 x 16B chunks; XOR
// swizzle chunk ^= (row&3) (applied on the GLOBAL source so global_load_lds
// dest stays linear; fragment reads XOR the chunk) -> conflict-free b128.
// Bijective XCD swizzle (m204). MFMA operands SWAPPED: acc[i][j] =
// mfma(bg[j], af[i]) -> row per-lane constant, 4 consecutive cols per acc ->
// packed 8B/16B stores.
#define VM_WAIT4 asm volatile("s_waitcnt vmcnt(4)" ::: "memory")
#define VM_WAIT0 asm volatile("s_waitcnt vmcnt(0)" ::: "memory")

#define GPHASE(BUF, KSR, IH, LOADBG, STG, WAITS) do {                        \
    if (LOADBG) {                                                            \
        const unsigned short* bb =                                           \
            &ls[(BUF) * 32768 + 16384 + (KSR) * 8192 + colOff];              \
        bg[0] = *(const bf16x8*)&bb[(wn +  0 + lane15) * 32];                \
        bg[1] = *(const bf16x8*)&bb[(wn + 16 + lane15) * 32];                \
        bg[2] = *(const bf16x8*)&bb[(wn + 32 + lane15) * 32];                \
        bg[3] = *(const bf16x8*)&bb[(wn + 48 + lane15) * 32];                \
    }                                                                        \
    {                                                                        \
        const unsigned short* ab =                                           \
            &ls[(BUF) * 32768 + (KSR) * 8192 + colOff];                      \
        af[0] = *(const bf16x8*)&ab[(wm + (IH)*64 +  0 + lane15) * 32];      \
        af[1] = *(const bf16x8*)&ab[(wm + (IH)*64 + 16 + lane15) * 32];      \
        af[2] = *(const bf16x8*)&ab[(wm + (IH)*64 + 32 + lane15) * 32];      \
        af[3] = *(const bf16x8*)&ab[(wm + (IH)*64 + 48 + lane15) * 32];      \
    }                                                                        \
    STG;                                                                     \
    WAITS;                                                                   \
    __builtin_amdgcn_s_barrier();                                            \
    asm volatile("s_waitcnt lgkmcnt(0)" ::: "memory");                       \
    __builtin_amdgcn_sched_barrier(0);                                       \
    __builtin_amdgcn_s_setprio(1);                                           \
    _Pragma("unroll")                                                        \
    for (int ii = 0; ii < 4; ++ii)                                           \
        _Pragma("unroll")                                                    \
        for (int j = 0; j < 4; ++j)                                          \
            acc[(IH)*4 + ii][j] = __builtin_amdgcn_mfma_f32_16x16x32_bf16(   \
                bg[j], af[ii], acc[(IH)*4 + ii][j], 0, 0, 0);                \
    __builtin_amdgcn_s_setprio(0);                                           \
    __builtin_amdgcn_s_barrier();                                            \
} while (0)

template <bool OUT_BF16>
__global__ __launch_bounds__(512, 2)
void gemm_bt256(const unsigned short* __restrict__ A,
                const unsigned short* __restrict__ Bt,
                const float* __restrict__ bias,
                void* __restrict__ Cv, int M, int N, int K) {
    // ls[buf][op][ks][256*32] ushorts; offsets: buf*32768 + op*16384 + ks*8192
    __shared__ alignas(16) unsigned short ls[65536];       // 128 KiB

    const int tid  = threadIdx.x;
    const int lane = tid & 63;
    const int wave = tid >> 6;          // 0..7
    const int wm = (wave >> 2) * 128;   // 0 / 128
    const int wn = (wave & 3) * 64;     // 0 / 64 / 128 / 192
    const int lane15 = lane & 15;
    const int quad   = lane >> 4;
    const int colOff = ((quad ^ (lane15 & 3)) * 8);        // swizzled chunk

    // bijective XCD swizzle (m204)
    const int nwg = (int)(gridDim.x * gridDim.y);
    const int hid = (int)(blockIdx.y * gridDim.x + blockIdx.x);
    const int q8  = nwg >> 3, r8 = nwg & 7;
    const int xcd = hid & 7;
    const int lid = (xcd < r8 ? xcd * (q8 + 1) : r8 * (q8 + 1) + (xcd - r8) * q8)
                    + (hid >> 3);
    const int tileX = lid % (int)gridDim.x;
    const int tileY = lid / (int)gridDim.x;
    const long bm = (long)tileY * 256;
    const long bn = (long)tileX * 256;

    // staging: thread t covers rows r0 = t/4 and r0+128, phys chunk t&3;
    // logical chunk lc = (t&3) ^ (r0&3) (r0&3 == (r0+128)&3).
    const int r0 = tid >> 2;
    const int lc = (tid & 3) ^ (r0 & 3);
    const unsigned short* gA0 = A  + (bm + r0)       * (long)K + lc * 8;
    const unsigned short* gA1 = A  + (bm + r0 + 128) * (long)K + lc * 8;
    const unsigned short* gB0 = Bt + (bn + r0)       * (long)K + lc * 8;
    const unsigned short* gB1 = Bt + (bn + r0 + 128) * (long)K + lc * 8;
    const int ldsWaveBase = wave * 512;    // within region (ushorts)

    // stage one region (op of {A=0,B=1}, K-half ksr of K-tile kt) -> buf
    auto STAGE = [&](int buf, int op, int ksr, int kt) {
        const int ko = kt * 64 + ksr * 32;
        unsigned short* d = &ls[buf * 32768 + op * 16384 + ksr * 8192 + ldsWaveBase];
        if (op == 0) {
            load16_to_lds(gA0 + ko, d);
            load16_to_lds(gA1 + ko, d + 4096);
        } else {
            load16_to_lds(gB0 + ko, d);
            load16_to_lds(gB1 + ko, d + 4096);
        }
    };

    f32x4 acc[8][4] = {};
    bf16x8 af[4], bg[4];

    const int NT = K >> 6;             // K-tiles (12); NI = NT/2 iterations
    const int NI = NT >> 1;

    // prologue: K-tile 0 (4 regions) + K-tile 1 k0 (2 regions)
    STAGE(0, 0, 0, 0); STAGE(0, 1, 0, 0); STAGE(0, 0, 1, 0); STAGE(0, 1, 1, 0);
    STAGE(1, 0, 0, 1); STAGE(1, 1, 0, 1);
    VM_WAIT4;                           // K-tile 0 fully landed (2 regions fly)
    __builtin_amdgcn_s_barrier();

    for (int i = 0; i < NI; ++i) {
        const int t2 = 2 * i;
        const bool last = (i == NI - 1);
        // ph0..3: consume buf0 (K-tile t2); ph4..7: buf1 (K-tile t2+1)
        GPHASE(0, 0, 0, 1, { STAGE(1, 0, 1, t2 + 1); }, { (void)0; });
        GPHASE(0, 0, 1, 0, { STAGE(1, 1, 1, t2 + 1); }, { (void)0; });
        GPHASE(0, 1, 0, 1, { if (!last) STAGE(0, 0, 0, t2 + 2); }, { (void)0; });
        GPHASE(0, 1, 1, 0, { if (!last) STAGE(0, 1, 0, t2 + 2); },
               { if (last) { VM_WAIT0; } else { VM_WAIT4; } });
        GPHASE(1, 0, 0, 1, { if (!last) STAGE(0, 0, 1, t2 + 2); }, { (void)0; });
        GPHASE(1, 0, 1, 0, { if (!last) STAGE(0, 1, 1, t2 + 2); }, { (void)0; });
        GPHASE(1, 1, 0, 1, { if (!last) STAGE(1, 0, 0, t2 + 3); }, { (void)0; });
        GPHASE(1, 1, 1, 0, { if (!last) { STAGE(1, 1, 0, t2 + 3); VM_WAIT4; } },
               { (void)0; });
    }

    // Epilogue: lane owns row = bm+wm+i*16+(lane&15), cols col0..col0+3.
    const long rbase = bm + wm + lane15;
    const int  cbase = (int)bn + wn + quad * 4;
    #pragma unroll
    for (int j = 0; j < 4; ++j) {
        const int col = cbase + j * 16;
        const float4 bv = *(const float4*)&bias[col];
        #pragma unroll
        for (int i = 0; i < 8; ++i) {
            const long row = rbase + i * 16;
            const size_t idx = (size_t)row * N + col;
            const float v0 = acc[i][j][0] + bv.x;
            const float v1 = acc[i][j][1] + bv.y;
            const float v2 = acc[i][j][2] + bv.z;
            const float v3 = acc[i][j][3] + bv.w;
            if constexpr (OUT_BF16) {
                ushort4 s;
                s.x = f2bf(v0); s.y = f2bf(v1); s.z = f2bf(v2); s.w = f2bf(v3);
                *(ushort4*)((unsigned short*)Cv + idx) = s;
            } else {
                float4 s;
                s.x = v0; s.y = v1; s.z = v2; s.w = v3;
                *(float4*)((float*)Cv + idx) = s;
            }
        }
    }
}

// ---------------- MFMA windowed attention ----------------
// One wave = one (b, w, head). 4 waves/block -> 4 heads (hg*4 + wave).
// qkv rows: token n = t*49 + w (t in [0,64)), cols sec*768 + h*64 + d.
// Pool q over token groups {j, j+16, j+32, j+48} -> qp[16][64] (in regs,
// pre-scaled by 0.125). S = qp @ k^T via 8 mfma (k frags from global).
// Softmax across 16 lanes + 4 n-tiles. P -> LDS -> A-frags. v staged
// transposed in LDS -> B-frags. O = P@v via 8 mfma. No __syncthreads.
__global__ __launch_bounds__(256)
void attn_win_mfma(const unsigned short* __restrict__ qkv,
                   unsigned short* __restrict__ o) {
    const int hg = blockIdx.x;       // 0..2
    const int w  = blockIdx.y;       // 0..48
    const int b  = blockIdx.z;       // batch within chunk
    const int wave = threadIdx.x >> 6;
    const int lane = threadIdx.x & 63;
    const int h = hg * 4 + wave;
    const int l = lane & 15;
    const int quad = lane >> 4;

    __shared__ alignas(16) unsigned short vT[4][64 * 72];  // [d][t], stride 72
    __shared__ alignas(16) unsigned short ps[4][16 * 72];  // P[q][key], stride 72

    const long tokStride = 49L * 2304;
    const long base = ((long)b * 3136 + w) * 2304 + h * 64;

    // ---- q load + max-pool + 0.125 scale (exact in bf16) -> A-frags ----
    bf16x8 af[2];
    {
        const unsigned short* qr = qkv + base + (long)l * tokStride + quad * 8;
        float m0[8], m1[8];
        #pragma unroll
        for (int sg = 0; sg < 4; ++sg) {
            uint4 u0 = *(const uint4*)(qr + (long)sg * 16 * tokStride);
            uint4 u1 = *(const uint4*)(qr + (long)sg * 16 * tokStride + 32);
            const unsigned short* p0 = (const unsigned short*)&u0;
            const unsigned short* p1 = (const unsigned short*)&u1;
            #pragma unroll
            for (int e = 0; e < 8; ++e) {
                float f0 = bf2f(p0[e]), f1 = bf2f(p1[e]);
                if (sg == 0) { m0[e] = f0; m1[e] = f1; }
                else { m0[e] = fmaxf(m0[e], f0); m1[e] = fmaxf(m1[e], f1); }
            }
        }
        u16x8 a0, a1;
        #pragma unroll
        for (int e = 0; e < 8; ++e) {
            a0[e] = f2bf(m0[e] * 0.125f);
            a1[e] = f2bf(m1[e] * 0.125f);
        }
        af[0] = __builtin_bit_cast(bf16x8, a0);
        af[1] = __builtin_bit_cast(bf16x8, a1);
    }

    // ---- v: stage transposed into LDS ----
    {
        const unsigned short* vr = qkv + base + (long)lane * tokStride + 1536;
        unsigned short* vw = &vT[wave][0];
        #pragma unroll
        for (int i = 0; i < 8; ++i) {
            uint4 u = *(const uint4*)(vr + i * 8);
            const unsigned short* pe = (const unsigned short*)&u;
            #pragma unroll
            for (int e = 0; e < 8; ++e)
                vw[(i * 8 + e) * 72 + lane] = pe[e];
        }
    }

    // ---- k B-frags from global; S = qp @ k^T ----
    f32x4 Sc[4] = {};
    {
        bf16x8 bk0, bk1;
        #pragma unroll
        for (int tt = 0; tt < 4; ++tt) {
            const unsigned short* kr =
                qkv + base + (long)(tt * 16 + l) * tokStride + 768 + quad * 8;
            bk0 = __builtin_bit_cast(bf16x8, *(const uint4*)kr);
            bk1 = __builtin_bit_cast(bf16x8, *(const uint4*)(kr + 32));
            Sc[tt] = __builtin_amdgcn_mfma_f32_16x16x32_bf16(af[0], bk0, Sc[tt], 0, 0, 0);
            Sc[tt] = __builtin_amdgcn_mfma_f32_16x16x32_bf16(af[1], bk1, Sc[tt], 0, 0, 0);
        }
    }

    // ---- softmax: row q = quad*4+r, keys spread over 4 tt x 16 lanes ----
    float pr[4][4];
    {
        #pragma unroll
        for (int r = 0; r < 4; ++r) {
            float mx = fmaxf(fmaxf(Sc[0][r], Sc[1][r]), fmaxf(Sc[2][r], Sc[3][r]));
            #pragma unroll
            for (int off = 1; off < 16; off <<= 1)
                mx = fmaxf(mx, __shfl_xor(mx, off));
            float sum = 0.f;
            #pragma unroll
            for (int tt = 0; tt < 4; ++tt) {
                pr[tt][r] = __expf(Sc[tt][r] - mx);
                sum += pr[tt][r];
            }
            #pragma unroll
            for (int off = 1; off < 16; off <<= 1)
                sum += __shfl_xor(sum, off);
            const float inv = 1.0f / sum;
            #pragma unroll
            for (int tt = 0; tt < 4; ++tt) pr[tt][r] *= inv;
        }
    }

    // ---- P -> LDS (bf16) ----
    {
        unsigned short* pw = &ps[wave][0];
        #pragma unroll
        for (int r = 0; r < 4; ++r)
            #pragma unroll
            for (int tt = 0; tt < 4; ++tt)
                pw[(quad * 4 + r) * 72 + tt * 16 + l] = f2bf(pr[tt][r]);
    }

    // ---- O = P @ v ----
    f32x4 Oc[4] = {};
    {
        #pragma unroll
        for (int s = 0; s < 2; ++s) {
            bf16x8 ap = *(const bf16x8*)&ps[wave][l * 72 + s * 32 + quad * 8];
            #pragma unroll
            for (int tt = 0; tt < 4; ++tt) {
                bf16x8 bv = *(const bf16x8*)&vT[wave][(tt * 16 + l) * 72 + s * 32 + quad * 8];
                Oc[tt] = __builtin_amdgcn_mfma_f32_16x16x32_bf16(ap, bv, Oc[tt], 0, 0, 0);
            }
        }
    }

    // ---- store: o row = b*784 + q*49 + w, col = h*64 + tt*16 + l ----
    {
        const long obase = ((long)b * 784 + (long)(quad * 4) * 49 + w) * 768 + h * 64 + l;
        #pragma unroll
        for (int tt = 0; tt < 4; ++tt)
            #pragma unroll
            for (int r = 0; r < 4; ++r)
                o[obase + (long)r * 49 * 768 + tt * 16] = f2bf(Oc[tt][r]);
    }
}

// ---------------- launcher ----------------
extern "C" void kernel_launch(void* const* d_in, const int* in_sizes, int n_in,
                              void* d_out, int out_size, void* d_ws, size_t ws_size,
                              hipStream_t stream) {
    const float* x     = (const float*)d_in[0];  // [32,3136,768]
    const float* Wqkv  = (const float*)d_in[1];  // [768,2304]
    const float* bqkv  = (const float*)d_in[2];  // [2304]
    const float* Wproj = (const float*)d_in[3];  // [768,768]
    const float* bproj = (const float*)d_in[4];  // [768]
    float* out = (float*)d_out;                  // [32,784,768] fp32

    const long needed1 = (32L * 3136 * 768 + 32L * 3136 * 2304 +
                          25088L * 768 + 2304L * 768 + 768L * 768) * 2;
    const int C  = (ws_size >= (size_t)needed1) ? 1 : 4;   // unchunked if ws allows
    const int CB = 32 / C;
    const long XC = (long)CB * 3136 * 768;
    const long QC = (long)CB * 3136 * 2304;

    char* p = (char*)d_ws;
    unsigned short* xb    = (unsigned short*)p; p += XC * 2;
    unsigned short* qkvb  = (unsigned short*)p; p += QC * 2;
    unsigned short* ob    = (unsigned short*)p; p += 25088L * 768 * 2;
    unsigned short* WqkvT = (unsigned short*)p; p += 2304L * 768 * 2;
    unsigned short* WprojT= (unsigned short*)p; p += 768L * 768 * 2;

    transpose_cvt<<<dim3(72, 24), 256, 0, stream>>>(Wqkv, WqkvT, 768, 2304);
    transpose_cvt<<<dim3(24, 24), 256, 0, stream>>>(Wproj, WprojT, 768, 768);

    const int M = CB * 3136;
    for (int c = 0; c < C; ++c) {
        cvt_f32_bf16<<<(int)(XC / 4 / 256), 256, 0, stream>>>(x + (size_t)c * XC, xb, XC / 4);
        gemm_bt256<true><<<dim3(9, M / 256), 512, 0, stream>>>(
            xb, WqkvT, bqkv, qkvb, M, 2304, 768);
        attn_win_mfma<<<dim3(3, 49, CB), 256, 0, stream>>>(
            qkvb, ob + (size_t)c * CB * 784 * 768);
    }
    gemm_bt256<false><<<dim3(3, 98), 512, 0, stream>>>(
        ob, WprojT, bproj, out, 25088, 768, 768);
}

// Round 4
// 1090.623 us; speedup vs baseline: 1.1281x; 1.0122x over previous
//
#include <hip/hip_runtime.h>
#include <hip/hip_bf16.h>

// MultiScaleAttention on MI355X (gfx950).
// cvt(x)->bf16; QKV GEMM (bf16 MFMA, 8-phase counted-vmcnt schedule);
// MFMA windowed attention; proj GEMM -> fp32 out. Unchunked (ws ~660MB ok).
// R4: R3's 8-phase schedule kept, but LDS layout restored to R2's
//     conflict-free form (256 rows x 64 k, 128 B/row, 8-chunk XOR swizzle;
//     R2 measured 0 bank conflicts). R3's 64 B/row 4-chunk regions caused a
//     4-way ds_read_b128 conflict (SQ_LDS_BANK_CONFLICT 3.25e7). Staging
//     regions are now row-QUARTERS (64 rows x 64 k = 8 KiB, exactly one
//     global_load_lds per thread): [buf][op] tile = 4 quarters.
//     Hazard-checked stage plan (region last-reader phase < re-stage phase):
//       ph0: A1q1,A1q3,B1q0(t+1) | ph1: B1q1,B1q2,B1q3 | ph2: -
//       ph3: A0q0,A0q2(t+2) + vmcnt(2) | ph4: A0q1,A0q3 | ph5: B0q0,B0q1
//       ph6: B0q2,B0q3 | ph7: A1q0,A1q2(t+3) + vmcnt(2)
//     (1 load/region/thread; waits keep 2 loads in flight, never drain to 0;
//      prologue 10 loads + vmcnt(2); last iter: ph3 wait = vmcnt(0), future
//      stages skipped.) K=768 -> 12 K-tiles, 6 iterations.

typedef __bf16 bf16x8 __attribute__((ext_vector_type(8)));
typedef float f32x4 __attribute__((ext_vector_type(4)));
typedef unsigned short u16x8 __attribute__((ext_vector_type(8)));

#define GLOBAL_AS __attribute__((address_space(1)))
#define LDS_AS __attribute__((address_space(3)))

__device__ __forceinline__ unsigned short f2bf(float f) {
    unsigned u = __builtin_bit_cast(unsigned, f);
    u += 0x7FFFu + ((u >> 16) & 1u);           // round-to-nearest-even
    return (unsigned short)(u >> 16);
}
__device__ __forceinline__ float bf2f(unsigned short h) {
    return __builtin_bit_cast(float, (unsigned)h << 16);
}

__device__ __forceinline__ void load16_to_lds(const void* g, void* l) {
    __builtin_amdgcn_global_load_lds((const GLOBAL_AS unsigned int*)g,
                                     (LDS_AS unsigned int*)l, 16, 0, 0);
}

// ---------------- elementwise fp32 -> bf16 ----------------
__global__ void cvt_f32_bf16(const float* __restrict__ in,
                             unsigned short* __restrict__ out, long n4) {
    long i = (long)blockIdx.x * blockDim.x + threadIdx.x;
    if (i >= n4) return;
    float4 f = ((const float4*)in)[i];
    uint2 u;
    u.x = (unsigned)f2bf(f.x) | ((unsigned)f2bf(f.y) << 16);
    u.y = (unsigned)f2bf(f.z) | ((unsigned)f2bf(f.w) << 16);
    ((uint2*)out)[i] = u;
}

// ---------------- W[K][N] fp32 -> Wt[N][K] bf16 ----------------
__global__ void transpose_cvt(const float* __restrict__ W,
                              unsigned short* __restrict__ Wt, int K, int N) {
    __shared__ float tile[32][33];
    int bx = blockIdx.x * 32;                  // N offset
    int by = blockIdx.y * 32;                  // K offset
    int tx = threadIdx.x & 31, ty = threadIdx.x >> 5;   // ty 0..7
    #pragma unroll
    for (int i = 0; i < 32; i += 8)
        tile[ty + i][tx] = W[(size_t)(by + ty + i) * N + bx + tx];
    __syncthreads();
    #pragma unroll
    for (int i = 0; i < 32; i += 8)
        Wt[(size_t)(bx + ty + i) * K + by + tx] = f2bf(tile[tx][ty + i]);
}

// ---------------- bf16 GEMM: C[M,N] = A[M,K] @ Bt[N,K]^T + bias ----------------
// 256x256 tile, BK=64, 512 threads = 8 waves (2M x 4N, per-wave 128x64 out),
// mfma 16x16x32, fp32 acc. 8-phase counted-vmcnt schedule (see header).
// LDS: [buf][op] tile = 256 rows x 64 k bf16 (32 KiB), 8 x 16B chunks/row;
// physical chunk p of row r holds logical chunk p^(r&7) (XOR applied on the
// GLOBAL source so global_load_lds dest stays linear; fragment reads XOR the
// chunk) -> conflict-free ds_read_b128 (verified 0 conflicts in R2).
// Bijective XCD swizzle (m204). MFMA operands SWAPPED: acc[i][j] =
// mfma(bg[j], af[i]) -> row per-lane constant, 4 consecutive cols per acc ->
// packed 8B/16B stores.
#define VM_WAIT2 asm volatile("s_waitcnt vmcnt(2)" ::: "memory")
#define VM_WAIT0 asm volatile("s_waitcnt vmcnt(0)" ::: "memory")

#define GPHASE(BUF, CSW, IH, LOADBG, STG, WAITS) do {                        \
    if (LOADBG) {                                                            \
        const unsigned short* bb = &ls[(BUF) * 32768 + 16384 + (CSW)];       \
        bg[0] = *(const bf16x8*)&bb[(wn +  0 + lane15) * 64];                \
        bg[1] = *(const bf16x8*)&bb[(wn + 16 + lane15) * 64];                \
        bg[2] = *(const bf16x8*)&bb[(wn + 32 + lane15) * 64];                \
        bg[3] = *(const bf16x8*)&bb[(wn + 48 + lane15) * 64];                \
    }                                                                        \
    {                                                                        \
        const unsigned short* ab = &ls[(BUF) * 32768 + (CSW)];               \
        af[0] = *(const bf16x8*)&ab[(wm + (IH)*64 +  0 + lane15) * 64];      \
        af[1] = *(const bf16x8*)&ab[(wm + (IH)*64 + 16 + lane15) * 64];      \
        af[2] = *(const bf16x8*)&ab[(wm + (IH)*64 + 32 + lane15) * 64];      \
        af[3] = *(const bf16x8*)&ab[(wm + (IH)*64 + 48 + lane15) * 64];      \
    }                                                                        \
    STG;                                                                     \
    WAITS;                                                                   \
    __builtin_amdgcn_s_barrier();                                            \
    asm volatile("s_waitcnt lgkmcnt(0)" ::: "memory");                       \
    __builtin_amdgcn_sched_barrier(0);                                       \
    __builtin_amdgcn_s_setprio(1);                                           \
    _Pragma("unroll")                                                        \
    for (int ii = 0; ii < 4; ++ii)                                           \
        _Pragma("unroll")                                                    \
        for (int j = 0; j < 4; ++j)                                          \
            acc[(IH)*4 + ii][j] = __builtin_amdgcn_mfma_f32_16x16x32_bf16(   \
                bg[j], af[ii], acc[(IH)*4 + ii][j], 0, 0, 0);                \
    __builtin_amdgcn_s_setprio(0);                                           \
    __builtin_amdgcn_s_barrier();                                            \
} while (0)

template <bool OUT_BF16>
__global__ __launch_bounds__(512, 2)
void gemm_bt256(const unsigned short* __restrict__ A,
                const unsigned short* __restrict__ Bt,
                const float* __restrict__ bias,
                void* __restrict__ Cv, int M, int N, int K) {
    // ls[buf][op][256*64] ushorts; tile offset = buf*32768 + op*16384;
    // quarter q (64 rows) at +q*4096.
    __shared__ alignas(16) unsigned short ls[65536];       // 128 KiB

    const int tid  = threadIdx.x;
    const int lane = tid & 63;
    const int wave = tid >> 6;          // 0..7
    const int wm = (wave >> 2) * 128;   // 0 / 128
    const int wn = (wave & 3) * 64;     // 0 / 64 / 128 / 192
    const int lane15 = lane & 15;
    const int quad   = lane >> 4;
    // logical chunk (ks/8 + quad) -> physical = logical ^ (row&7), row&7 = lane&7
    const int csw0 = ((quad    ) ^ (lane & 7)) * 8;        // ks = 0
    const int csw1 = ((quad + 4) ^ (lane & 7)) * 8;        // ks = 32

    // bijective XCD swizzle (m204)
    const int nwg = (int)(gridDim.x * gridDim.y);
    const int hid = (int)(blockIdx.y * gridDim.x + blockIdx.x);
    const int q8  = nwg >> 3, r8 = nwg & 7;
    const int xcd = hid & 7;
    const int lid = (xcd < r8 ? xcd * (q8 + 1) : r8 * (q8 + 1) + (xcd - r8) * q8)
                    + (hid >> 3);
    const int tileX = lid % (int)gridDim.x;
    const int tileY = lid / (int)gridDim.x;
    const long bm = (long)tileY * 256;
    const long bn = (long)tileX * 256;

    // staging: thread t covers row (t>>3) within a 64-row quarter, physical
    // chunk t&7 -> global (logical) chunk lc = (t&7) ^ (row&7).
    const int r0 = tid >> 3;                               // 0..63
    const int lc = (tid & 7) ^ (r0 & 7);
    const unsigned short* gA = A  + (bm + r0) * (long)K + lc * 8;
    const unsigned short* gB = Bt + (bn + r0) * (long)K + lc * 8;
    const int ldsWaveBase = wave * 512;    // ushorts (8 rows per wave)

    // stage quarter q (rows q*64..q*64+63) of op tile for K-tile kt -> buf
    auto STAGE_A = [&](int buf, int q, int kt) {
        load16_to_lds(gA + (long)q * 64 * K + kt * 64,
                      &ls[buf * 32768 + q * 4096 + ldsWaveBase]);
    };
    auto STAGE_B = [&](int buf, int q, int kt) {
        load16_to_lds(gB + (long)q * 64 * K + kt * 64,
                      &ls[buf * 32768 + 16384 + q * 4096 + ldsWaveBase]);
    };

    f32x4 acc[8][4] = {};
    bf16x8 af[4], bg[4];

    const int NT = K >> 6;             // K-tiles (12); NI = NT/2 iterations
    const int NI = NT >> 1;

    // prologue: K-tile 0 (8 quarters) + K-tile 1 A-q0/q2 -> 10 loads
    STAGE_A(0, 0, 0); STAGE_A(0, 1, 0); STAGE_A(0, 2, 0); STAGE_A(0, 3, 0);
    STAGE_B(0, 0, 0); STAGE_B(0, 1, 0); STAGE_B(0, 2, 0); STAGE_B(0, 3, 0);
    STAGE_A(1, 0, 1); STAGE_A(1, 2, 1);
    VM_WAIT2;                           // K-tile 0 landed (A1q0,q2 in flight)
    __builtin_amdgcn_s_barrier();

    for (int i = 0; i < NI; ++i) {
        const int t2 = 2 * i;
        const bool last = (i == NI - 1);
        // ph0..3: consume buf0 (K-tile t2); ph4..7: buf1 (K-tile t2+1)
        GPHASE(0, csw0, 0, 1,
               { STAGE_A(1, 1, t2 + 1); STAGE_A(1, 3, t2 + 1); STAGE_B(1, 0, t2 + 1); },
               { (void)0; });
        GPHASE(0, csw0, 1, 0,
               { STAGE_B(1, 1, t2 + 1); STAGE_B(1, 2, t2 + 1); STAGE_B(1, 3, t2 + 1); },
               { (void)0; });
        GPHASE(0, csw1, 0, 1, { (void)0; }, { (void)0; });
        GPHASE(0, csw1, 1, 0,
               { if (!last) { STAGE_A(0, 0, t2 + 2); STAGE_A(0, 2, t2 + 2); } },
               { if (last) { VM_WAIT0; } else { VM_WAIT2; } });
        GPHASE(1, csw0, 0, 1,
               { if (!last) { STAGE_A(0, 1, t2 + 2); STAGE_A(0, 3, t2 + 2); } },
               { (void)0; });
        GPHASE(1, csw0, 1, 0,
               { if (!last) { STAGE_B(0, 0, t2 + 2); STAGE_B(0, 1, t2 + 2); } },
               { (void)0; });
        GPHASE(1, csw1, 0, 1,
               { if (!last) { STAGE_B(0, 2, t2 + 2); STAGE_B(0, 3, t2 + 2); } },
               { (void)0; });
        GPHASE(1, csw1, 1, 0,
               { if (!last) { STAGE_A(1, 0, t2 + 3); STAGE_A(1, 2, t2 + 3); VM_WAIT2; } },
               { (void)0; });
    }

    // Epilogue: lane owns row = bm+wm+i*16+(lane&15), cols col0..col0+3.
    const long rbase = bm + wm + lane15;
    const int  cbase = (int)bn + wn + quad * 4;
    #pragma unroll
    for (int j = 0; j < 4; ++j) {
        const int col = cbase + j * 16;
        const float4 bv = *(const float4*)&bias[col];
        #pragma unroll
        for (int i = 0; i < 8; ++i) {
            const long row = rbase + i * 16;
            const size_t idx = (size_t)row * N + col;
            const float v0 = acc[i][j][0] + bv.x;
            const float v1 = acc[i][j][1] + bv.y;
            const float v2 = acc[i][j][2] + bv.z;
            const float v3 = acc[i][j][3] + bv.w;
            if constexpr (OUT_BF16) {
                ushort4 s;
                s.x = f2bf(v0); s.y = f2bf(v1); s.z = f2bf(v2); s.w = f2bf(v3);
                *(ushort4*)((unsigned short*)Cv + idx) = s;
            } else {
                float4 s;
                s.x = v0; s.y = v1; s.z = v2; s.w = v3;
                *(float4*)((float*)Cv + idx) = s;
            }
        }
    }
}

// ---------------- MFMA windowed attention ----------------
// One wave = one (b, w, head). 4 waves/block -> 4 heads (hg*4 + wave).
// qkv rows: token n = t*49 + w (t in [0,64)), cols sec*768 + h*64 + d.
// Pool q over token groups {j, j+16, j+32, j+48} -> qp[16][64] (in regs,
// pre-scaled by 0.125). S = qp @ k^T via 8 mfma (k frags from global).
// Softmax across 16 lanes + 4 n-tiles. P -> LDS -> A-frags. v staged
// transposed in LDS -> B-frags. O = P@v via 8 mfma. No __syncthreads.
__global__ __launch_bounds__(256)
void attn_win_mfma(const unsigned short* __restrict__ qkv,
                   unsigned short* __restrict__ o) {
    const int hg = blockIdx.x;       // 0..2
    const int w  = blockIdx.y;       // 0..48
    const int b  = blockIdx.z;       // batch within chunk
    const int wave = threadIdx.x >> 6;
    const int lane = threadIdx.x & 63;
    const int h = hg * 4 + wave;
    const int l = lane & 15;
    const int quad = lane >> 4;

    __shared__ alignas(16) unsigned short vT[4][64 * 72];  // [d][t], stride 72
    __shared__ alignas(16) unsigned short ps[4][16 * 72];  // P[q][key], stride 72

    const long tokStride = 49L * 2304;
    const long base = ((long)b * 3136 + w) * 2304 + h * 64;

    // ---- q load + max-pool + 0.125 scale (exact in bf16) -> A-frags ----
    bf16x8 af[2];
    {
        const unsigned short* qr = qkv + base + (long)l * tokStride + quad * 8;
        float m0[8], m1[8];
        #pragma unroll
        for (int sg = 0; sg < 4; ++sg) {
            uint4 u0 = *(const uint4*)(qr + (long)sg * 16 * tokStride);
            uint4 u1 = *(const uint4*)(qr + (long)sg * 16 * tokStride + 32);
            const unsigned short* p0 = (const unsigned short*)&u0;
            const unsigned short* p1 = (const unsigned short*)&u1;
            #pragma unroll
            for (int e = 0; e < 8; ++e) {
                float f0 = bf2f(p0[e]), f1 = bf2f(p1[e]);
                if (sg == 0) { m0[e] = f0; m1[e] = f1; }
                else { m0[e] = fmaxf(m0[e], f0); m1[e] = fmaxf(m1[e], f1); }
            }
        }
        u16x8 a0, a1;
        #pragma unroll
        for (int e = 0; e < 8; ++e) {
            a0[e] = f2bf(m0[e] * 0.125f);
            a1[e] = f2bf(m1[e] * 0.125f);
        }
        af[0] = __builtin_bit_cast(bf16x8, a0);
        af[1] = __builtin_bit_cast(bf16x8, a1);
    }

    // ---- v: stage transposed into LDS ----
    {
        const unsigned short* vr = qkv + base + (long)lane * tokStride + 1536;
        unsigned short* vw = &vT[wave][0];
        #pragma unroll
        for (int i = 0; i < 8; ++i) {
            uint4 u = *(const uint4*)(vr + i * 8);
            const unsigned short* pe = (const unsigned short*)&u;
            #pragma unroll
            for (int e = 0; e < 8; ++e)
                vw[(i * 8 + e) * 72 + lane] = pe[e];
        }
    }

    // ---- k B-frags from global; S = qp @ k^T ----
    f32x4 Sc[4] = {};
    {
        bf16x8 bk0, bk1;
        #pragma unroll
        for (int tt = 0; tt < 4; ++tt) {
            const unsigned short* kr =
                qkv + base + (long)(tt * 16 + l) * tokStride + 768 + quad * 8;
            bk0 = __builtin_bit_cast(bf16x8, *(const uint4*)kr);
            bk1 = __builtin_bit_cast(bf16x8, *(const uint4*)(kr + 32));
            Sc[tt] = __builtin_amdgcn_mfma_f32_16x16x32_bf16(af[0], bk0, Sc[tt], 0, 0, 0);
            Sc[tt] = __builtin_amdgcn_mfma_f32_16x16x32_bf16(af[1], bk1, Sc[tt], 0, 0, 0);
        }
    }

    // ---- softmax: row q = quad*4+r, keys spread over 4 tt x 16 lanes ----
    float pr[4][4];
    {
        #pragma unroll
        for (int r = 0; r < 4; ++r) {
            float mx = fmaxf(fmaxf(Sc[0][r], Sc[1][r]), fmaxf(Sc[2][r], Sc[3][r]));
            #pragma unroll
            for (int off = 1; off < 16; off <<= 1)
                mx = fmaxf(mx, __shfl_xor(mx, off));
            float sum = 0.f;
            #pragma unroll
            for (int tt = 0; tt < 4; ++tt) {
                pr[tt][r] = __expf(Sc[tt][r] - mx);
                sum += pr[tt][r];
            }
            #pragma unroll
            for (int off = 1; off < 16; off <<= 1)
                sum += __shfl_xor(sum, off);
            const float inv = 1.0f / sum;
            #pragma unroll
            for (int tt = 0; tt < 4; ++tt) pr[tt][r] *= inv;
        }
    }

    // ---- P -> LDS (bf16) ----
    {
        unsigned short* pw = &ps[wave][0];
        #pragma unroll
        for (int r = 0; r < 4; ++r)
            #pragma unroll
            for (int tt = 0; tt < 4; ++tt)
                pw[(quad * 4 + r) * 72 + tt * 16 + l] = f2bf(pr[tt][r]);
    }

    // ---- O = P @ v ----
    f32x4 Oc[4] = {};
    {
        #pragma unroll
        for (int s = 0; s < 2; ++s) {
            bf16x8 ap = *(const bf16x8*)&ps[wave][l * 72 + s * 32 + quad * 8];
            #pragma unroll
            for (int tt = 0; tt < 4; ++tt) {
                bf16x8 bv = *(const bf16x8*)&vT[wave][(tt * 16 + l) * 72 + s * 32 + quad * 8];
                Oc[tt] = __builtin_amdgcn_mfma_f32_16x16x32_bf16(ap, bv, Oc[tt], 0, 0, 0);
            }
        }
    }

    // ---- store: o row = b*784 + q*49 + w, col = h*64 + tt*16 + l ----
    {
        const long obase = ((long)b * 784 + (long)(quad * 4) * 49 + w) * 768 + h * 64 + l;
        #pragma unroll
        for (int tt = 0; tt < 4; ++tt)
            #pragma unroll
            for (int r = 0; r < 4; ++r)
                o[obase + (long)r * 49 * 768 + tt * 16] = f2bf(Oc[tt][r]);
    }
}

// ---------------- launcher ----------------
extern "C" void kernel_launch(void* const* d_in, const int* in_sizes, int n_in,
                              void* d_out, int out_size, void* d_ws, size_t ws_size,
                              hipStream_t stream) {
    const float* x     = (const float*)d_in[0];  // [32,3136,768]
    const float* Wqkv  = (const float*)d_in[1];  // [768,2304]
    const float* bqkv  = (const float*)d_in[2];  // [2304]
    const float* Wproj = (const float*)d_in[3];  // [768,768]
    const float* bproj = (const float*)d_in[4];  // [768]
    float* out = (float*)d_out;                  // [32,784,768] fp32

    const long needed1 = (32L * 3136 * 768 + 32L * 3136 * 2304 +
                          25088L * 768 + 2304L * 768 + 768L * 768) * 2;
    const int C  = (ws_size >= (size_t)needed1) ? 1 : 4;   // unchunked if ws allows
    const int CB = 32 / C;
    const long XC = (long)CB * 3136 * 768;
    const long QC = (long)CB * 3136 * 2304;

    char* p = (char*)d_ws;
    unsigned short* xb    = (unsigned short*)p; p += XC * 2;
    unsigned short* qkvb  = (unsigned short*)p; p += QC * 2;
    unsigned short* ob    = (unsigned short*)p; p += 25088L * 768 * 2;
    unsigned short* WqkvT = (unsigned short*)p; p += 2304L * 768 * 2;
    unsigned short* WprojT= (unsigned short*)p; p += 768L * 768 * 2;

    transpose_cvt<<<dim3(72, 24), 256, 0, stream>>>(Wqkv, WqkvT, 768, 2304);
    transpose_cvt<<<dim3(24, 24), 256, 0, stream>>>(Wproj, WprojT, 768, 768);

    const int M = CB * 3136;
    for (int c = 0; c < C; ++c) {
        cvt_f32_bf16<<<(int)(XC / 4 / 256), 256, 0, stream>>>(x + (size_t)c * XC, xb, XC / 4);
        gemm_bt256<true><<<dim3(9, M / 256), 512, 0, stream>>>(
            xb, WqkvT, bqkv, qkvb, M, 2304, 768);
        attn_win_mfma<<<dim3(3, 49, CB), 256, 0, stream>>>(
            qkvb, ob + (size_t)c * CB * 784 * 768);
    }
    gemm_bt256<false><<<dim3(3, 98), 512, 0, stream>>>(
        ob, WprojT, bproj, out, 25088, 768, 768);
}

// Round 5
// 1067.530 us; speedup vs baseline: 1.1525x; 1.0216x over previous
//
#include <hip/hip_runtime.h>
#include <hip/hip_bf16.h>

// MultiScaleAttention on MI355X (gfx950).
// R5: window-contiguous qkv layout to fix attn's DRAM-row-bound gathers.
//   - cvt permutes x rows: row' = b*3136 + w*64 + t  (w=n%49, t=n/49)
//   - QKV GEMM epilogue writes qkv as [b][w][sec=3][h=12][t=64][d=64]
//     (each wave's 64-col slab = one (sec,h); rows are window-major so the
//     per-window slab is 294 KB contiguous)
//   - attn reads contiguous slabs (tokStride 225792B -> 128B): streaming.
//   - QKV GEMM split into 2 half-M dispatches (diagnostic visibility; if the
//     attn theory is wrong it enters top-5 with counters next round).
// GEMM core: 256x256 tile, 8 waves, BK=64, 8-phase counted-vmcnt schedule
// (R4), conflict-free XOR-swizzled LDS (0 conflicts measured), bijective XCD
// swizzle, swapped-operand packed epilogue.

typedef __bf16 bf16x8 __attribute__((ext_vector_type(8)));
typedef float f32x4 __attribute__((ext_vector_type(4)));
typedef unsigned short u16x8 __attribute__((ext_vector_type(8)));

#define GLOBAL_AS __attribute__((address_space(1)))
#define LDS_AS __attribute__((address_space(3)))

__device__ __forceinline__ unsigned short f2bf(float f) {
    unsigned u = __builtin_bit_cast(unsigned, f);
    u += 0x7FFFu + ((u >> 16) & 1u);           // round-to-nearest-even
    return (unsigned short)(u >> 16);
}
__device__ __forceinline__ float bf2f(unsigned short h) {
    return __builtin_bit_cast(float, (unsigned)h << 16);
}

__device__ __forceinline__ void load16_to_lds(const void* g, void* l) {
    __builtin_amdgcn_global_load_lds((const GLOBAL_AS unsigned int*)g,
                                     (LDS_AS unsigned int*)l, 16, 0, 0);
}

// ---------------- fp32 -> bf16 with window-major row permute ----------------
// in:  [nRows][768] fp32, row g = b*3136 + t*49 + w
// out: [nRows][768] bf16, row' = b*3136 + w*64 + t
__global__ void cvt_permute(const float* __restrict__ in,
                            unsigned short* __restrict__ out, int nRows) {
    const long idx = (long)blockIdx.x * blockDim.x + threadIdx.x;  // f4 granule
    if (idx >= (long)nRows * 192) return;
    const int g  = (int)(idx / 192);
    const int c4 = (int)(idx - (long)g * 192);
    const int b  = g / 3136;
    const int nn = g - b * 3136;
    const int t  = nn / 49;
    const int w  = nn - t * 49;
    float4 f = ((const float4*)in)[idx];
    uint2 u;
    u.x = (unsigned)f2bf(f.x) | ((unsigned)f2bf(f.y) << 16);
    u.y = (unsigned)f2bf(f.z) | ((unsigned)f2bf(f.w) << 16);
    ((uint2*)out)[(long)(b * 3136 + w * 64 + t) * 192 + c4] = u;
}

// ---------------- W[K][N] fp32 -> Wt[N][K] bf16 ----------------
__global__ void transpose_cvt(const float* __restrict__ W,
                              unsigned short* __restrict__ Wt, int K, int N) {
    __shared__ float tile[32][33];
    int bx = blockIdx.x * 32;                  // N offset
    int by = blockIdx.y * 32;                  // K offset
    int tx = threadIdx.x & 31, ty = threadIdx.x >> 5;   // ty 0..7
    #pragma unroll
    for (int i = 0; i < 32; i += 8)
        tile[ty + i][tx] = W[(size_t)(by + ty + i) * N + bx + tx];
    __syncthreads();
    #pragma unroll
    for (int i = 0; i < 32; i += 8)
        Wt[(size_t)(bx + ty + i) * K + by + tx] = f2bf(tile[tx][ty + i]);
}

// ---------------- bf16 GEMM: C = A[M,K] @ Bt[N,K]^T + bias ----------------
// OUT_BF16=true : QKV path -> writes [b][w][3][12][64][64] bf16 (A rows are
//                 window-major permuted tokens; mBase = global row offset).
// OUT_BF16=false: proj path -> canonical fp32 [row][N].
#define VM_WAIT2 asm volatile("s_waitcnt vmcnt(2)" ::: "memory")
#define VM_WAIT0 asm volatile("s_waitcnt vmcnt(0)" ::: "memory")

#define GPHASE(BUF, CSW, IH, LOADBG, STG, WAITS) do {                        \
    if (LOADBG) {                                                            \
        const unsigned short* bb = &ls[(BUF) * 32768 + 16384 + (CSW)];       \
        bg[0] = *(const bf16x8*)&bb[(wn +  0 + lane15) * 64];                \
        bg[1] = *(const bf16x8*)&bb[(wn + 16 + lane15) * 64];                \
        bg[2] = *(const bf16x8*)&bb[(wn + 32 + lane15) * 64];                \
        bg[3] = *(const bf16x8*)&bb[(wn + 48 + lane15) * 64];                \
    }                                                                        \
    {                                                                        \
        const unsigned short* ab = &ls[(BUF) * 32768 + (CSW)];               \
        af[0] = *(const bf16x8*)&ab[(wm + (IH)*64 +  0 + lane15) * 64];      \
        af[1] = *(const bf16x8*)&ab[(wm + (IH)*64 + 16 + lane15) * 64];      \
        af[2] = *(const bf16x8*)&ab[(wm + (IH)*64 + 32 + lane15) * 64];      \
        af[3] = *(const bf16x8*)&ab[(wm + (IH)*64 + 48 + lane15) * 64];      \
    }                                                                        \
    STG;                                                                     \
    WAITS;                                                                   \
    __builtin_amdgcn_s_barrier();                                            \
    asm volatile("s_waitcnt lgkmcnt(0)" ::: "memory");                       \
    __builtin_amdgcn_sched_barrier(0);                                       \
    __builtin_amdgcn_s_setprio(1);                                           \
    _Pragma("unroll")                                                        \
    for (int ii = 0; ii < 4; ++ii)                                           \
        _Pragma("unroll")                                                    \
        for (int j = 0; j < 4; ++j)                                          \
            acc[(IH)*4 + ii][j] = __builtin_amdgcn_mfma_f32_16x16x32_bf16(   \
                bg[j], af[ii], acc[(IH)*4 + ii][j], 0, 0, 0);                \
    __builtin_amdgcn_s_setprio(0);                                           \
    __builtin_amdgcn_s_barrier();                                            \
} while (0)

template <bool OUT_BF16>
__global__ __launch_bounds__(512, 2)
void gemm_bt256(const unsigned short* __restrict__ A,
                const unsigned short* __restrict__ Bt,
                const float* __restrict__ bias,
                void* __restrict__ Cv, int mBase, int N, int K) {
    // ls[buf][op][256*64] ushorts; tile offset = buf*32768 + op*16384;
    // quarter q (64 rows) at +q*4096.
    __shared__ alignas(16) unsigned short ls[65536];       // 128 KiB

    const int tid  = threadIdx.x;
    const int lane = tid & 63;
    const int wave = tid >> 6;          // 0..7
    const int wm = (wave >> 2) * 128;   // 0 / 128
    const int wn = (wave & 3) * 64;     // 0 / 64 / 128 / 192
    const int lane15 = lane & 15;
    const int quad   = lane >> 4;
    // logical chunk (ks/8 + quad) -> physical = logical ^ (row&7), row&7 = lane&7
    const int csw0 = ((quad    ) ^ (lane & 7)) * 8;        // ks = 0
    const int csw1 = ((quad + 4) ^ (lane & 7)) * 8;        // ks = 32

    // bijective XCD swizzle (m204)
    const int nwg = (int)(gridDim.x * gridDim.y);
    const int hid = (int)(blockIdx.y * gridDim.x + blockIdx.x);
    const int q8  = nwg >> 3, r8 = nwg & 7;
    const int xcd = hid & 7;
    const int lid = (xcd < r8 ? xcd * (q8 + 1) : r8 * (q8 + 1) + (xcd - r8) * q8)
                    + (hid >> 3);
    const int tileX = lid % (int)gridDim.x;
    const int tileY = lid / (int)gridDim.x;
    const long bm = (long)tileY * 256;
    const long bn = (long)tileX * 256;

    // staging: thread t covers row (t>>3) within a 64-row quarter, physical
    // chunk t&7 -> global (logical) chunk lc = (t&7) ^ (row&7).
    const int r0 = tid >> 3;                               // 0..63
    const int lc = (tid & 7) ^ (r0 & 7);
    const unsigned short* gA = A  + (bm + r0) * (long)K + lc * 8;
    const unsigned short* gB = Bt + (bn + r0) * (long)K + lc * 8;
    const int ldsWaveBase = wave * 512;    // ushorts (8 rows per wave)

    auto STAGE_A = [&](int buf, int q, int kt) {
        load16_to_lds(gA + (long)q * 64 * K + kt * 64,
                      &ls[buf * 32768 + q * 4096 + ldsWaveBase]);
    };
    auto STAGE_B = [&](int buf, int q, int kt) {
        load16_to_lds(gB + (long)q * 64 * K + kt * 64,
                      &ls[buf * 32768 + 16384 + q * 4096 + ldsWaveBase]);
    };

    f32x4 acc[8][4] = {};
    bf16x8 af[4], bg[4];

    const int NT = K >> 6;             // K-tiles (12); NI = NT/2 iterations
    const int NI = NT >> 1;

    // prologue: K-tile 0 (8 quarters) + K-tile 1 A-q0/q2 -> 10 loads
    STAGE_A(0, 0, 0); STAGE_A(0, 1, 0); STAGE_A(0, 2, 0); STAGE_A(0, 3, 0);
    STAGE_B(0, 0, 0); STAGE_B(0, 1, 0); STAGE_B(0, 2, 0); STAGE_B(0, 3, 0);
    STAGE_A(1, 0, 1); STAGE_A(1, 2, 1);
    VM_WAIT2;                           // K-tile 0 landed (A1q0,q2 in flight)
    __builtin_amdgcn_s_barrier();

    for (int i = 0; i < NI; ++i) {
        const int t2 = 2 * i;
        const bool last = (i == NI - 1);
        // ph0..3: consume buf0 (K-tile t2); ph4..7: buf1 (K-tile t2+1)
        GPHASE(0, csw0, 0, 1,
               { STAGE_A(1, 1, t2 + 1); STAGE_A(1, 3, t2 + 1); STAGE_B(1, 0, t2 + 1); },
               { (void)0; });
        GPHASE(0, csw0, 1, 0,
               { STAGE_B(1, 1, t2 + 1); STAGE_B(1, 2, t2 + 1); STAGE_B(1, 3, t2 + 1); },
               { (void)0; });
        GPHASE(0, csw1, 0, 1, { (void)0; }, { (void)0; });
        GPHASE(0, csw1, 1, 0,
               { if (!last) { STAGE_A(0, 0, t2 + 2); STAGE_A(0, 2, t2 + 2); } },
               { if (last) { VM_WAIT0; } else { VM_WAIT2; } });
        GPHASE(1, csw0, 0, 1,
               { if (!last) { STAGE_A(0, 1, t2 + 2); STAGE_A(0, 3, t2 + 2); } },
               { (void)0; });
        GPHASE(1, csw0, 1, 0,
               { if (!last) { STAGE_B(0, 0, t2 + 2); STAGE_B(0, 1, t2 + 2); } },
               { (void)0; });
        GPHASE(1, csw1, 0, 1,
               { if (!last) { STAGE_B(0, 2, t2 + 2); STAGE_B(0, 3, t2 + 2); } },
               { (void)0; });
        GPHASE(1, csw1, 1, 0,
               { if (!last) { STAGE_A(1, 0, t2 + 3); STAGE_A(1, 2, t2 + 3); VM_WAIT2; } },
               { (void)0; });
    }

    // Epilogue: lane owns row = mBase+bm+wm+i*16+lane15, cols cbase..cbase+3.
    const int rbase = (int)(bm) + wm + lane15;
    if constexpr (OUT_BF16) {
        // QKV layout: [b][w][sec][h][t][d]; wave's 64-col slab = one (sec,h)
        const int colBase = (int)bn + wn;              // multiple of 64
        const int sec = colBase / 768;
        const int hh  = (colBase - sec * 768) >> 6;
        const long shOff = (long)sec * 49152 + hh * 4096 + quad * 4;
        unsigned short* qout = (unsigned short*)Cv;
        float4 bv[4];
        #pragma unroll
        for (int j = 0; j < 4; ++j)
            bv[j] = *(const float4*)&bias[colBase + quad * 4 + j * 16];
        #pragma unroll
        for (int i = 0; i < 8; ++i) {
            const int m  = mBase + rbase + i * 16;     // window-major token idx
            const int b  = m / 3136;
            const int r3 = m - b * 3136;               // = w*64 + t
            unsigned short* rp = qout + (long)(b * 49 + (r3 >> 6)) * 147456
                                      + shOff + (long)(r3 & 63) * 64;
            #pragma unroll
            for (int j = 0; j < 4; ++j) {
                ushort4 s;
                s.x = f2bf(acc[i][j][0] + bv[j].x);
                s.y = f2bf(acc[i][j][1] + bv[j].y);
                s.z = f2bf(acc[i][j][2] + bv[j].z);
                s.w = f2bf(acc[i][j][3] + bv[j].w);
                *(ushort4*)(rp + j * 16) = s;
            }
        }
    } else {
        const int cbase = (int)bn + wn + quad * 4;
        #pragma unroll
        for (int j = 0; j < 4; ++j) {
            const int col = cbase + j * 16;
            const float4 bv = *(const float4*)&bias[col];
            #pragma unroll
            for (int i = 0; i < 8; ++i) {
                const long row = (long)mBase + rbase + i * 16;
                const size_t idx = (size_t)row * N + col;
                float4 s;
                s.x = acc[i][j][0] + bv.x;
                s.y = acc[i][j][1] + bv.y;
                s.z = acc[i][j][2] + bv.z;
                s.w = acc[i][j][3] + bv.w;
                *(float4*)((float*)Cv + idx) = s;
            }
        }
    }
}

// ---------------- MFMA windowed attention ----------------
// qkv layout: [b][w][sec][h][t][d] (t=64 tokens, d=64) -> all reads are
// contiguous 8KB slabs per (sec,h). One wave = one (b,w,head); 4 waves/block.
// Pool q over token groups {j, j+16, j+32, j+48} -> qp[16][64] (in regs,
// pre-scaled by 0.125). S = qp @ k^T via 8 mfma (k frags from global).
// Softmax across 16 lanes + 4 n-tiles. P -> LDS -> A-frags. v staged
// transposed in LDS -> B-frags. O = P@v via 8 mfma. No __syncthreads.
__global__ __launch_bounds__(256)
void attn_win_mfma(const unsigned short* __restrict__ qkv,
                   unsigned short* __restrict__ o) {
    const int hg = blockIdx.x;       // 0..2
    const int w  = blockIdx.y;       // 0..48
    const int b  = blockIdx.z;       // batch within chunk
    const int wave = threadIdx.x >> 6;
    const int lane = threadIdx.x & 63;
    const int h = hg * 4 + wave;
    const int l = lane & 15;
    const int quad = lane >> 4;

    __shared__ alignas(16) unsigned short vT[4][64 * 72];  // [d][t], stride 72
    __shared__ alignas(16) unsigned short ps[4][16 * 72];  // P[q][key], stride 72

    const long slab = (long)(b * 49 + w) * 147456;
    const long hOff = (long)h * 4096;

    // ---- q load + max-pool + 0.125 scale (exact in bf16) -> A-frags ----
    bf16x8 af[2];
    {
        const unsigned short* qr = qkv + slab + hOff + (long)l * 64 + quad * 8;
        float m0[8], m1[8];
        #pragma unroll
        for (int sg = 0; sg < 4; ++sg) {
            uint4 u0 = *(const uint4*)(qr + sg * 1024);
            uint4 u1 = *(const uint4*)(qr + sg * 1024 + 32);
            const unsigned short* p0 = (const unsigned short*)&u0;
            const unsigned short* p1 = (const unsigned short*)&u1;
            #pragma unroll
            for (int e = 0; e < 8; ++e) {
                float f0 = bf2f(p0[e]), f1 = bf2f(p1[e]);
                if (sg == 0) { m0[e] = f0; m1[e] = f1; }
                else { m0[e] = fmaxf(m0[e], f0); m1[e] = fmaxf(m1[e], f1); }
            }
        }
        u16x8 a0, a1;
        #pragma unroll
        for (int e = 0; e < 8; ++e) {
            a0[e] = f2bf(m0[e] * 0.125f);
            a1[e] = f2bf(m1[e] * 0.125f);
        }
        af[0] = __builtin_bit_cast(bf16x8, a0);
        af[1] = __builtin_bit_cast(bf16x8, a1);
    }

    // ---- v: stage transposed into LDS ----
    {
        const unsigned short* vr = qkv + slab + 98304 + hOff + (long)lane * 64;
        unsigned short* vw = &vT[wave][0];
        #pragma unroll
        for (int i = 0; i < 8; ++i) {
            uint4 u = *(const uint4*)(vr + i * 8);
            const unsigned short* pe = (const unsigned short*)&u;
            #pragma unroll
            for (int e = 0; e < 8; ++e)
                vw[(i * 8 + e) * 72 + lane] = pe[e];
        }
    }

    // ---- k B-frags from global; S = qp @ k^T ----
    f32x4 Sc[4] = {};
    {
        bf16x8 bk0, bk1;
        #pragma unroll
        for (int tt = 0; tt < 4; ++tt) {
            const unsigned short* kr =
                qkv + slab + 49152 + hOff + (long)(tt * 16 + l) * 64 + quad * 8;
            bk0 = __builtin_bit_cast(bf16x8, *(const uint4*)kr);
            bk1 = __builtin_bit_cast(bf16x8, *(const uint4*)(kr + 32));
            Sc[tt] = __builtin_amdgcn_mfma_f32_16x16x32_bf16(af[0], bk0, Sc[tt], 0, 0, 0);
            Sc[tt] = __builtin_amdgcn_mfma_f32_16x16x32_bf16(af[1], bk1, Sc[tt], 0, 0, 0);
        }
    }

    // ---- softmax: row q = quad*4+r, keys spread over 4 tt x 16 lanes ----
    float pr[4][4];
    {
        #pragma unroll
        for (int r = 0; r < 4; ++r) {
            float mx = fmaxf(fmaxf(Sc[0][r], Sc[1][r]), fmaxf(Sc[2][r], Sc[3][r]));
            #pragma unroll
            for (int off = 1; off < 16; off <<= 1)
                mx = fmaxf(mx, __shfl_xor(mx, off));
            float sum = 0.f;
            #pragma unroll
            for (int tt = 0; tt < 4; ++tt) {
                pr[tt][r] = __expf(Sc[tt][r] - mx);
                sum += pr[tt][r];
            }
            #pragma unroll
            for (int off = 1; off < 16; off <<= 1)
                sum += __shfl_xor(sum, off);
            const float inv = 1.0f / sum;
            #pragma unroll
            for (int tt = 0; tt < 4; ++tt) pr[tt][r] *= inv;
        }
    }

    // ---- P -> LDS (bf16) ----
    {
        unsigned short* pw = &ps[wave][0];
        #pragma unroll
        for (int r = 0; r < 4; ++r)
            #pragma unroll
            for (int tt = 0; tt < 4; ++tt)
                pw[(quad * 4 + r) * 72 + tt * 16 + l] = f2bf(pr[tt][r]);
    }

    // ---- O = P @ v ----
    f32x4 Oc[4] = {};
    {
        #pragma unroll
        for (int s = 0; s < 2; ++s) {
            bf16x8 ap = *(const bf16x8*)&ps[wave][l * 72 + s * 32 + quad * 8];
            #pragma unroll
            for (int tt = 0; tt < 4; ++tt) {
                bf16x8 bv = *(const bf16x8*)&vT[wave][(tt * 16 + l) * 72 + s * 32 + quad * 8];
                Oc[tt] = __builtin_amdgcn_mfma_f32_16x16x32_bf16(ap, bv, Oc[tt], 0, 0, 0);
            }
        }
    }

    // ---- store: o row = b*784 + q*49 + w, col = h*64 + tt*16 + l ----
    {
        const long obase = ((long)b * 784 + (long)(quad * 4) * 49 + w) * 768 + h * 64 + l;
        #pragma unroll
        for (int tt = 0; tt < 4; ++tt)
            #pragma unroll
            for (int r = 0; r < 4; ++r)
                o[obase + (long)r * 49 * 768 + tt * 16] = f2bf(Oc[tt][r]);
    }
}

// ---------------- launcher ----------------
extern "C" void kernel_launch(void* const* d_in, const int* in_sizes, int n_in,
                              void* d_out, int out_size, void* d_ws, size_t ws_size,
                              hipStream_t stream) {
    const float* x     = (const float*)d_in[0];  // [32,3136,768]
    const float* Wqkv  = (const float*)d_in[1];  // [768,2304]
    const float* bqkv  = (const float*)d_in[2];  // [2304]
    const float* Wproj = (const float*)d_in[3];  // [768,768]
    const float* bproj = (const float*)d_in[4];  // [768]
    float* out = (float*)d_out;                  // [32,784,768] fp32

    const long needed1 = (32L * 3136 * 768 + 32L * 3136 * 2304 +
                          25088L * 768 + 2304L * 768 + 768L * 768) * 2;
    const int C  = (ws_size >= (size_t)needed1) ? 1 : 4;   // unchunked if ws allows
    const int CB = 32 / C;
    const long XC = (long)CB * 3136 * 768;
    const long QC = (long)CB * 3136 * 2304;

    char* p = (char*)d_ws;
    unsigned short* xb    = (unsigned short*)p; p += XC * 2;
    unsigned short* qkvb  = (unsigned short*)p; p += QC * 2;
    unsigned short* ob    = (unsigned short*)p; p += 25088L * 768 * 2;
    unsigned short* WqkvT = (unsigned short*)p; p += 2304L * 768 * 2;
    unsigned short* WprojT= (unsigned short*)p; p += 768L * 768 * 2;

    transpose_cvt<<<dim3(72, 24), 256, 0, stream>>>(Wqkv, WqkvT, 768, 2304);
    transpose_cvt<<<dim3(24, 24), 256, 0, stream>>>(Wproj, WprojT, 768, 768);

    const int M  = CB * 3136;
    const int Mh = M / 2;                        // multiple of 256 for CB in {8,32}
    for (int c = 0; c < C; ++c) {
        const int nRows = M;
        cvt_permute<<<(int)(((long)nRows * 192 + 255) / 256), 256, 0, stream>>>(
            x + (size_t)c * XC, xb, nRows);
        gemm_bt256<true><<<dim3(9, Mh / 256), 512, 0, stream>>>(
            xb, WqkvT, bqkv, qkvb, 0, 2304, 768);
        gemm_bt256<true><<<dim3(9, Mh / 256), 512, 0, stream>>>(
            xb + (long)Mh * 768, WqkvT, bqkv, qkvb, Mh, 2304, 768);
        attn_win_mfma<<<dim3(3, 49, CB), 256, 0, stream>>>(
            qkvb, ob + (size_t)c * CB * 784 * 768);
    }
    gemm_bt256<false><<<dim3(3, 98), 512, 0, stream>>>(
        ob, WprojT, bproj, out, 0, 768, 768);
}